// Round 11
// baseline (896.407 us; speedup 1.0000x reference)
//
#include <hip/hip_runtime.h>

#define NN 100000
#define NE 1600000
#define NADJ 2
#define NLAY 3
#define HD 128
#define NG 1024

#define SCAN_BLOCKS ((NN + 255) / 256)   // 391

typedef unsigned int uint32;
typedef unsigned short u16;

typedef __attribute__((ext_vector_type(8))) short bfrag8;   // 8 bf16 (4 VGPR)
typedef __attribute__((ext_vector_type(4))) float f32x4;
typedef __attribute__((ext_vector_type(2))) float f32x2;

__device__ __forceinline__ u16 f2bf(float f) {   // RNE pack
    uint32 u = __float_as_uint(f);
    u += 0x7FFFu + ((u >> 16) & 1u);
    return (u16)(u >> 16);
}
__device__ __forceinline__ float bflo(uint32 u) { return __uint_as_float(u << 16); }
__device__ __forceinline__ float bfhi(uint32 u) { return __uint_as_float(u & 0xFFFF0000u); }

// x (fp32) -> bf16, 8 elems/thread; grid covers NN*HD/8 EXACTLY (6250 blocks)
__global__ __launch_bounds__(256) void to_bf16(const float* __restrict__ in,
                                               u16* __restrict__ o) {
    int i = blockIdx.x * 256 + threadIdx.x;
    float4 a = ((const float4*)in)[i * 2];
    float4 b = ((const float4*)in)[i * 2 + 1];
    uint4 v;
    v.x = (uint32)f2bf(a.x) | ((uint32)f2bf(a.y) << 16);
    v.y = (uint32)f2bf(a.z) | ((uint32)f2bf(a.w) << 16);
    v.z = (uint32)f2bf(b.x) | ((uint32)f2bf(b.y) << 16);
    v.w = (uint32)f2bf(b.z) | ((uint32)f2bf(b.w) << 16);
    ((uint4*)o)[i] = v;
}

// one-time: wt[b][n][k] = bf16(W_b[k][n]); b in [0,6) -> conv, b==6 -> lin0_w
__global__ void wt_prep(const float* __restrict__ conv_w,
                        const float* __restrict__ lin0_w, u16* __restrict__ wt) {
    const float* W = (blockIdx.x < 6) ? conv_w + (size_t)blockIdx.x * HD * HD
                                      : lin0_w;
    u16* o = wt + (size_t)blockIdx.x * HD * HD;
    for (int i = 0; i < 64; ++i) {
        int idx = i * 256 + threadIdx.x;
        int n = idx >> 7, k = idx & 127;
        o[idx] = f2bf(W[k * 128 + n]);
    }
}

// ---------------- MFMA GEMM, LDS-free: out = bf16( post( A @ W ) ) ----------
__global__ __launch_bounds__(256) void gemm_mfma(
    const u16* __restrict__ Abf, const u16* __restrict__ Wt,
    u16* __restrict__ outbf, const float* __restrict__ dis,
    const float* __restrict__ bias, int relu)
{
    const int wid = blockIdx.x * 4 + (threadIdx.x >> 6);
    const int lane = threadIdx.x & 63;
    const int row0 = (wid >> 1) * 64;
    if (row0 >= NN) return;
    const int wc = (wid & 1) * 64;
    const int lr = lane & 15, kg = lane >> 4;

    bfrag8 b[4][4];
    #pragma unroll
    for (int ks = 0; ks < 4; ++ks)
        #pragma unroll
        for (int j = 0; j < 4; ++j)
            b[ks][j] = *(const bfrag8*)&Wt[(size_t)(wc + j * 16 + lr) * 128
                                           + (ks * 4 + kg) * 8];

    const f32x4 z = {0.f, 0.f, 0.f, 0.f};
    f32x4 acc[4][4];
    #pragma unroll
    for (int i = 0; i < 4; ++i)
        #pragma unroll
        for (int j = 0; j < 4; ++j) acc[i][j] = z;

    #pragma unroll
    for (int ks = 0; ks < 4; ++ks) {          // K = 4 x 32
        bfrag8 a[4];
        #pragma unroll
        for (int i = 0; i < 4; ++i) {
            int r = min(row0 + i * 16 + lr, NN - 1);   // tail clamp
            a[i] = *(const bfrag8*)&Abf[(size_t)r * 128 + (ks * 4 + kg) * 8];
        }
        #pragma unroll
        for (int i = 0; i < 4; ++i)
            #pragma unroll
            for (int j = 0; j < 4; ++j)
                acc[i][j] = __builtin_amdgcn_mfma_f32_16x16x32_bf16(
                    a[i], b[ks][j], acc[i][j], 0, 0, 0);
    }

    // C/D: col = lane&15, row = (lane>>4)*4 + reg   [m89-verified]
    #pragma unroll
    for (int i = 0; i < 4; ++i) {
        #pragma unroll
        for (int r = 0; r < 4; ++r) {
            int grow = row0 + i * 16 + kg * 4 + r;
            if (grow < NN) {
                float ds = dis ? dis[grow] : 1.f;
                #pragma unroll
                for (int j = 0; j < 4; ++j) {
                    int gcol = wc + j * 16 + lr;
                    float o = acc[i][j][r] * ds;
                    if (bias) o += bias[gcol];
                    if (relu) o = fmaxf(o, 0.f);
                    outbf[(size_t)grow * 128 + gcol] = f2bf(o);
                }
            }
        }
    }
}

// 8-way split histogram; 4 edges/thread so 4 independent returning atomics
// are in flight per wave (was latency-bound at 1: R10). copy(e)=(e>>8)&7.
__global__ __launch_bounds__(256) void hist_plocal(
    const int* __restrict__ col, int* __restrict__ cnt8,
    int* __restrict__ p_local) {
    int base = blockIdx.x * 1024 + threadIdx.x;
    int cc[4]; bool ok[4];
    #pragma unroll
    for (int u = 0; u < 4; ++u) {
        int ee = base + u * 256;
        ok[u] = ee < NE;
        cc[u] = ok[u] ? col[ee] : 0;
    }
    int pp[4];
    #pragma unroll
    for (int u = 0; u < 4; ++u) {
        int ee = base + u * 256;
        if (ok[u])
            pp[u] = atomicAdd(&cnt8[((ee >> 8) & 7) * NN + cc[u]], 1);
    }
    #pragma unroll
    for (int u = 0; u < 4; ++u) {
        int ee = base + u * 256;
        if (ok[u]) p_local[ee] = pp[u];
    }
}

// per node: total cnt + per-copy exclusive offsets + fused block sums
__global__ __launch_bounds__(256) void combine_hist(
    const int* __restrict__ cnt8, int* __restrict__ cnt,
    int* __restrict__ copyoff, int* __restrict__ bsum) {
    __shared__ int ws[4];
    int i = blockIdx.x * 256 + threadIdx.x;
    int s = 0;
    if (i < NN) {
        #pragma unroll
        for (int c = 0; c < 8; ++c) {
            int v = cnt8[c * NN + i];
            copyoff[c * NN + i] = s;
            s += v;
        }
        cnt[i] = s;
    }
    int v = s;
    #pragma unroll
    for (int off = 32; off > 0; off >>= 1) v += __shfl_xor(v, off);
    if ((threadIdx.x & 63) == 0) ws[threadIdx.x >> 6] = v;
    __syncthreads();
    if (threadIdx.x == 0) bsum[blockIdx.x] = ws[0] + ws[1] + ws[2] + ws[3];
}

__global__ __launch_bounds__(512) void scan_bsums(int* __restrict__ bsum)
{
    __shared__ int s[512];
    int t = threadIdx.x;
    int v = (t < SCAN_BLOCKS) ? bsum[t] : 0;
    s[t] = v;
    __syncthreads();
    #pragma unroll
    for (int off = 1; off < 512; off <<= 1) {
        int u = (t >= off) ? s[t - off] : 0;
        __syncthreads();
        s[t] += u;
        __syncthreads();
    }
    if (t < SCAN_BLOCKS) bsum[t] = s[t] - v;   // exclusive
}

__global__ __launch_bounds__(256) void write_rowptr(
    const int* __restrict__ cnt, const int* __restrict__ bsum,
    int* __restrict__ row_ptr, float* __restrict__ dis)
{
    __shared__ int s[256];
    int t = threadIdx.x;
    int i = blockIdx.x * 256 + t;
    int v = (i < NN) ? cnt[i] : 0;
    s[t] = v;
    __syncthreads();
    #pragma unroll
    for (int off = 1; off < 256; off <<= 1) {
        int u = (t >= off) ? s[t - off] : 0;
        __syncthreads();
        s[t] += u;
        __syncthreads();
    }
    if (i < NN) {
        int excl = bsum[blockIdx.x] + s[t] - v;
        row_ptr[i] = excl;
        dis[i] = rsqrtf((float)(v + 1));   // +1 self loop
        if (i == NN - 1) row_ptr[NN] = excl + v;
    }
}

// atomic-free scatter; 4 independent load->load->store chains per thread
__global__ __launch_bounds__(256) void scatter_edges(
    const int* __restrict__ row, const int* __restrict__ col,
    const int* __restrict__ p_local, const int* __restrict__ row_ptr,
    const int* __restrict__ copyoff, int* __restrict__ csr_src)
{
    int base = blockIdx.x * 1024 + threadIdx.x;
    int cc[4], rr[4], pl[4]; bool ok[4];
    #pragma unroll
    for (int u = 0; u < 4; ++u) {
        int ee = base + u * 256;
        ok[u] = ee < NE;
        int es = ok[u] ? ee : 0;
        cc[u] = col[es];
        rr[u] = row[es];
        pl[u] = p_local[es];
    }
    int slot[4];
    #pragma unroll
    for (int u = 0; u < 4; ++u) {
        int ee = base + u * 256;
        slot[u] = row_ptr[cc[u]] + copyoff[((ee >> 8) & 7) * NN + cc[u]] + pl[u];
    }
    #pragma unroll
    for (int u = 0; u < 4; ++u)
        if (ok[u]) __builtin_nontemporal_store(rr[u], &csr_src[slot[u]]);
}

// out[i] = bf16( relu( dis[i] * ( mm[i] + sum_e mm[src_e] ) ) ), one wave/node.
// v_pk_add_f32 adds both unpacked channels in one VOP3P (4->3 VALU/edge);
// per-channel values/order identical -> bitwise-same result.
__global__ __launch_bounds__(256) void agg_relu(
    const u16* __restrict__ mm, const int* __restrict__ row_ptr,
    const int* __restrict__ csr_src,
    const float* __restrict__ dis, u16* __restrict__ out)
{
    int node = blockIdx.x * 4 + (threadIdx.x >> 6);
    if (node >= NN) return;
    uint32 lane = threadIdx.x & 63;
    const uint32* mv = (const uint32*)mm;
    uint32 self = mv[(uint32)node * 64u + lane];
    f32x2 acc2;
    acc2.x = bflo(self);
    acc2.y = bfhi(self);
    int e0 = row_ptr[node], e1 = row_ptr[node + 1];

    int e = e0;
    for (; e + 16 <= e1; e += 16) {
        uint32 ss[16];
        #pragma unroll
        for (int u = 0; u < 16; ++u) ss[u] = (uint32)csr_src[e + u];
        uint32 vv[16];
        #pragma unroll
        for (int u = 0; u < 16; ++u)
            vv[u] = mv[ss[u] * 64u + lane];
        #pragma unroll
        for (int u = 0; u < 16; ++u) {
            f32x2 t;
            t.x = bflo(vv[u]);
            t.y = bfhi(vv[u]);
            asm("v_pk_add_f32 %0, %0, %1" : "+v"(acc2) : "v"(t));
        }
    }
    float accx = acc2.x, accy = acc2.y;
    int rem = e1 - e;
    if (rem > 8) {          // 9..15: one masked 16-wide
        uint32 ss[16];
        float mk[16];
        #pragma unroll
        for (int u = 0; u < 16; ++u) {
            int idx = e + u;
            ss[u] = (uint32)csr_src[min(idx, e1 - 1)];
            mk[u] = (idx < e1) ? 1.f : 0.f;
        }
        uint32 vv[16];
        #pragma unroll
        for (int u = 0; u < 16; ++u)
            vv[u] = mv[ss[u] * 64u + lane];
        #pragma unroll
        for (int u = 0; u < 16; ++u) {
            accx = fmaf(mk[u], bflo(vv[u]), accx);
            accy = fmaf(mk[u], bfhi(vv[u]), accy);
        }
    } else if (rem > 0) {   // 1..8: one masked 8-wide
        uint32 ss[8];
        float mk[8];
        #pragma unroll
        for (int u = 0; u < 8; ++u) {
            int idx = e + u;
            ss[u] = (uint32)csr_src[min(idx, e1 - 1)];
            mk[u] = (idx < e1) ? 1.f : 0.f;
        }
        uint32 vv[8];
        #pragma unroll
        for (int u = 0; u < 8; ++u)
            vv[u] = mv[ss[u] * 64u + lane];
        #pragma unroll
        for (int u = 0; u < 8; ++u) {
            accx = fmaf(mk[u], bflo(vv[u]), accx);
            accy = fmaf(mk[u], bfhi(vv[u]), accy);
        }
    }

    float d = dis[node];
    uint32 po = (uint32)f2bf(fmaxf(d * accx, 0.f))
              | ((uint32)f2bf(fmaxf(d * accy, 0.f)) << 16);
    ((uint32*)out)[(uint32)node * 64u + lane] = po;
}

// pooled[batch[n]][aoff + 2c..2c+1] += h[n][2c..2c+1]; 64 threads, uint32 loads
__global__ __launch_bounds__(64) void pool_add(
    const u16* __restrict__ h, const int* __restrict__ batch,
    float* __restrict__ pooled, int aoff)
{
    int c2 = threadIdx.x;                 // col pair
    const uint32* hv = (const uint32*)h;
    int n0 = blockIdx.x * 64;
    int nend = min(n0 + 64, NN);
    int cur = batch[n0];
    float ax = 0.f, ay = 0.f;
    for (int n = n0; n < nend; ++n) {
        int g = batch[n];
        if (g != cur) {
            atomicAdd(&pooled[(size_t)cur * 256 + aoff + 2 * c2], ax);
            atomicAdd(&pooled[(size_t)cur * 256 + aoff + 2 * c2 + 1], ay);
            ax = 0.f; ay = 0.f;
            cur = g;
        }
        uint32 v = hv[(size_t)n * 64 + c2];
        ax += bflo(v);
        ay += bfhi(v);
    }
    atomicAdd(&pooled[(size_t)cur * 256 + aoff + 2 * c2], ax);
    atomicAdd(&pooled[(size_t)cur * 256 + aoff + 2 * c2 + 1], ay);
}

// out[g] = relu(pooled[g] @ w1 + b1) @ w2 + b2
__global__ __launch_bounds__(128) void head(
    const float* __restrict__ pooled,
    const float* __restrict__ w1, const float* __restrict__ b1,
    const float* __restrict__ w2, const float* __restrict__ b2,
    float* __restrict__ out)
{
    __shared__ float sp[256];
    __shared__ float sg[128];
    int g = blockIdx.x, t = threadIdx.x;
    sp[t] = pooled[(size_t)g * 256 + t];
    sp[t + 128] = pooled[(size_t)g * 256 + 128 + t];
    __syncthreads();
    float acc = b1[t];
    #pragma unroll 8
    for (int k = 0; k < 256; ++k) acc = fmaf(sp[k], w1[k * 128 + t], acc);
    sg[t] = fmaxf(acc, 0.f) * w2[t];
    __syncthreads();
    for (int s2 = 64; s2 > 0; s2 >>= 1) {
        if (t < s2) sg[t] += sg[t + s2];
        __syncthreads();
    }
    if (t == 0) out[g] = sg[0] + b2[0];
}

extern "C" void kernel_launch(void* const* d_in, const int* in_sizes, int n_in,
                              void* d_out, int out_size, void* d_ws, size_t ws_size,
                              hipStream_t stream) {
    const float* x      = (const float*)d_in[0];
    const int*   ei     = (const int*)d_in[1];
    const int*   batch  = (const int*)d_in[2];
    const float* lin0_w = (const float*)d_in[3];
    const float* lin0_b = (const float*)d_in[4];
    const float* conv_w = (const float*)d_in[5];
    const float* lin1_w = (const float*)d_in[6];
    const float* lin1_b = (const float*)d_in[7];
    const float* lin2_w = (const float*)d_in[8];
    const float* lin2_b = (const float*)d_in[9];
    float* out = (float*)d_out;

    const size_t NB = (size_t)NN * HD;
    float* x0f    = (float*)d_ws;              // first half: x0 bf16; second: xbf
    float* bufA   = x0f + NB;                  // mm (bf16); also p_local
    float* bufB   = bufA + NB;                 // h (bf16)
    float* pooled = bufB + NB;
    int*   cnt     = (int*)(pooled + (size_t)NG * 256);
    int*   row_ptr = cnt + NN;
    float* dis     = (float*)(row_ptr + NN + 1);
    int*   csr_src = (int*)(dis + NN);
    int*   bsum    = csr_src + NE;
    u16*   wt      = (u16*)(bsum + 512);       // 7 x 128 x 128 bf16 = 224 KB
    int*   cnt8    = (int*)(wt + 7 * HD * HD); // 8 x NN = 3.2 MB
    int*   copyoff = cnt8 + 8 * NN;            // 8 x NN = 3.2 MB

    u16* x0bf    = (u16*)x0f;                  // NB bf16 = 25.6 MB
    u16* xbf     = (u16*)(x0f + NB / 2);       // x as bf16, 25.6 MB
    u16* mm      = (u16*)bufA;
    u16* hbuf    = (u16*)bufB;
    int* p_local = (int*)bufA;   // dead before first conv gemm writes mm

    const int GEMM_BLOCKS = (((NN + 63) / 64) * 2 + 3) / 4;   // 782
    const int EDGE4_BLOCKS = (NE + 1023) / 1024;              // 1563

    hipMemsetAsync(pooled, 0, (size_t)NG * 256 * sizeof(float), stream);

    to_bf16<<<NN * HD / 8 / 256, 256, 0, stream>>>(x, xbf);
    wt_prep<<<NADJ * NLAY + 1, 256, 0, stream>>>(conv_w, lin0_w, wt);

    // x0 = bf16(relu(x @ lin0_w + lin0_b))   via MFMA
    gemm_mfma<<<GEMM_BLOCKS, 256, 0, stream>>>(
        xbf, wt + 6 * HD * HD, x0bf, nullptr, lin0_b, 1);

    for (int a = 0; a < NADJ; ++a) {
        const int* row = ei + (size_t)a * 2 * NE;
        const int* col = row + NE;

        hipMemsetAsync(cnt8, 0, 8 * NN * sizeof(int), stream);
        hist_plocal<<<EDGE4_BLOCKS, 256, 0, stream>>>(col, cnt8, p_local);
        combine_hist<<<SCAN_BLOCKS, 256, 0, stream>>>(cnt8, cnt, copyoff, bsum);
        scan_bsums<<<1, 512, 0, stream>>>(bsum);
        write_rowptr<<<SCAN_BLOCKS, 256, 0, stream>>>(cnt, bsum, row_ptr, dis);
        scatter_edges<<<EDGE4_BLOCKS, 256, 0, stream>>>(row, col, p_local,
                                                        row_ptr, copyoff,
                                                        csr_src);

        const u16* h = x0bf;
        for (int l = 0; l < NLAY; ++l) {
            const u16* Wt = wt + ((size_t)a * NLAY + l) * HD * HD;
            gemm_mfma<<<GEMM_BLOCKS, 256, 0, stream>>>(h, Wt, mm, dis,
                                                       nullptr, 0);
            agg_relu<<<(NN + 3) / 4, 256, 0, stream>>>(mm, row_ptr, csr_src,
                                                       dis, hbuf);
            h = hbuf;
        }
        pool_add<<<(NN + 63) / 64, 64, 0, stream>>>(hbuf, batch, pooled, a * HD);
    }

    head<<<NG, 128, 0, stream>>>(pooled, lin1_w, lin1_b, lin2_w, lin2_b, out);
}

// Round 12
// 745.071 us; speedup vs baseline: 1.2031x; 1.2031x over previous
//
#include <hip/hip_runtime.h>

#define NN 100000
#define NE 1600000
#define NADJ 2
#define NLAY 3
#define HD 128
#define NG 1024

#define EB   1563    // edge blocks of 1024
#define NBUK 391     // col buckets of 256 nodes
#define BPAD 400     // padded bucket stride

typedef unsigned int uint32;
typedef unsigned short u16;

typedef __attribute__((ext_vector_type(8))) short bfrag8;   // 8 bf16 (4 VGPR)
typedef __attribute__((ext_vector_type(4))) float f32x4;
typedef __attribute__((ext_vector_type(2))) float f32x2;

__device__ __forceinline__ u16 f2bf(float f) {   // RNE pack
    uint32 u = __float_as_uint(f);
    u += 0x7FFFu + ((u >> 16) & 1u);
    return (u16)(u >> 16);
}
__device__ __forceinline__ float bflo(uint32 u) { return __uint_as_float(u << 16); }
__device__ __forceinline__ float bfhi(uint32 u) { return __uint_as_float(u & 0xFFFF0000u); }

// x (fp32) -> bf16, 8 elems/thread; grid covers NN*HD/8 EXACTLY (6250 blocks)
__global__ __launch_bounds__(256) void to_bf16(const float* __restrict__ in,
                                               u16* __restrict__ o) {
    int i = blockIdx.x * 256 + threadIdx.x;
    float4 a = ((const float4*)in)[i * 2];
    float4 b = ((const float4*)in)[i * 2 + 1];
    uint4 v;
    v.x = (uint32)f2bf(a.x) | ((uint32)f2bf(a.y) << 16);
    v.y = (uint32)f2bf(a.z) | ((uint32)f2bf(a.w) << 16);
    v.z = (uint32)f2bf(b.x) | ((uint32)f2bf(b.y) << 16);
    v.w = (uint32)f2bf(b.z) | ((uint32)f2bf(b.w) << 16);
    ((uint4*)o)[i] = v;
}

// one-time: wt[b][n][k] = bf16(W_b[k][n]); b in [0,6) -> conv, b==6 -> lin0_w
__global__ void wt_prep(const float* __restrict__ conv_w,
                        const float* __restrict__ lin0_w, u16* __restrict__ wt) {
    const float* W = (blockIdx.x < 6) ? conv_w + (size_t)blockIdx.x * HD * HD
                                      : lin0_w;
    u16* o = wt + (size_t)blockIdx.x * HD * HD;
    for (int i = 0; i < 64; ++i) {
        int idx = i * 256 + threadIdx.x;
        int n = idx >> 7, k = idx & 127;
        o[idx] = f2bf(W[k * 128 + n]);
    }
}

// ---------------- MFMA GEMM, LDS-free: out = bf16( post( A @ W ) ) ----------
__global__ __launch_bounds__(256) void gemm_mfma(
    const u16* __restrict__ Abf, const u16* __restrict__ Wt,
    u16* __restrict__ outbf, const float* __restrict__ dis,
    const float* __restrict__ bias, int relu)
{
    const int wid = blockIdx.x * 4 + (threadIdx.x >> 6);
    const int lane = threadIdx.x & 63;
    const int row0 = (wid >> 1) * 64;
    if (row0 >= NN) return;
    const int wc = (wid & 1) * 64;
    const int lr = lane & 15, kg = lane >> 4;

    bfrag8 b[4][4];
    #pragma unroll
    for (int ks = 0; ks < 4; ++ks)
        #pragma unroll
        for (int j = 0; j < 4; ++j)
            b[ks][j] = *(const bfrag8*)&Wt[(size_t)(wc + j * 16 + lr) * 128
                                           + (ks * 4 + kg) * 8];

    const f32x4 z = {0.f, 0.f, 0.f, 0.f};
    f32x4 acc[4][4];
    #pragma unroll
    for (int i = 0; i < 4; ++i)
        #pragma unroll
        for (int j = 0; j < 4; ++j) acc[i][j] = z;

    #pragma unroll
    for (int ks = 0; ks < 4; ++ks) {          // K = 4 x 32
        bfrag8 a[4];
        #pragma unroll
        for (int i = 0; i < 4; ++i) {
            int r = min(row0 + i * 16 + lr, NN - 1);   // tail clamp
            a[i] = *(const bfrag8*)&Abf[(size_t)r * 128 + (ks * 4 + kg) * 8];
        }
        #pragma unroll
        for (int i = 0; i < 4; ++i)
            #pragma unroll
            for (int j = 0; j < 4; ++j)
                acc[i][j] = __builtin_amdgcn_mfma_f32_16x16x32_bf16(
                    a[i], b[ks][j], acc[i][j], 0, 0, 0);
    }

    // C/D: col = lane&15, row = (lane>>4)*4 + reg   [m89-verified]
    #pragma unroll
    for (int i = 0; i < 4; ++i) {
        #pragma unroll
        for (int r = 0; r < 4; ++r) {
            int grow = row0 + i * 16 + kg * 4 + r;
            if (grow < NN) {
                float ds = dis ? dis[grow] : 1.f;
                #pragma unroll
                for (int j = 0; j < 4; ++j) {
                    int gcol = wc + j * 16 + lr;
                    float o = acc[i][j][r] * ds;
                    if (bias) o += bias[gcol];
                    if (relu) o = fmaxf(o, 0.f);
                    outbf[(size_t)grow * 128 + gcol] = f2bf(o);
                }
            }
        }
    }
}

// ============ atomic-free CSR build: two-level counting sort ============
// Global-atomic throughput (~24 G/s returning) was the wall (R10/R11);
// this pipeline uses only LDS atomics + scans + plain stores.

// P1: per-block LDS histogram over col buckets (col>>8)
__global__ __launch_bounds__(256) void p1_count(
    const int* __restrict__ col, int* __restrict__ bcnt)
{
    __shared__ int h[NBUK];
    int t = threadIdx.x;
    for (int q = t; q < NBUK; q += 256) h[q] = 0;
    __syncthreads();
    int base = blockIdx.x * 1024 + t;
    #pragma unroll
    for (int u = 0; u < 4; ++u) {
        int e = base + u * 256;
        if (e < NE) atomicAdd(&h[col[e] >> 8], 1);
    }
    __syncthreads();
    for (int q = t; q < NBUK; q += 256)
        bcnt[blockIdx.x * BPAD + q] = h[q];
}

// P2a: per bucket, exclusive scan over the EB block-counts + bucket total
__global__ __launch_bounds__(256) void p2a_scanblocks(
    const int* __restrict__ bcnt, int* __restrict__ pscan,
    int* __restrict__ btot)
{
    __shared__ int s[256];
    int b = blockIdx.x;
    int t = threadIdx.x;
    int v[7];
    int loc = 0;
    #pragma unroll
    for (int j = 0; j < 7; ++j) {
        int idx = t * 7 + j;
        v[j] = (idx < EB) ? bcnt[idx * BPAD + b] : 0;
        loc += v[j];
    }
    s[t] = loc;
    __syncthreads();
    for (int off = 1; off < 256; off <<= 1) {
        int u = (t >= off) ? s[t - off] : 0;
        __syncthreads();
        s[t] += u;
        __syncthreads();
    }
    int pre = s[t] - loc;
    #pragma unroll
    for (int j = 0; j < 7; ++j) {
        int idx = t * 7 + j;
        if (idx < EB) pscan[idx * BPAD + b] = pre;
        pre += v[j];
    }
    if (t == 255) btot[b] = s[255];
}

// P2b: exclusive scan over bucket totals -> bbase[0..NBUK], bbase[NBUK]=NE
__global__ __launch_bounds__(512) void p2b_scanbuckets(
    const int* __restrict__ btot, int* __restrict__ bbase)
{
    __shared__ int s[512];
    int t = threadIdx.x;
    int v = (t < NBUK) ? btot[t] : 0;
    s[t] = v;
    __syncthreads();
    for (int off = 1; off < 512; off <<= 1) {
        int u = (t >= off) ? s[t - off] : 0;
        __syncthreads();
        s[t] += u;
        __syncthreads();
    }
    if (t < NBUK) bbase[t] = s[t] - v;
    if (t == NBUK - 1) bbase[NBUK] = s[t];
}

// P3: partition edges into bucket regions (LDS ranks, plain global stores)
__global__ __launch_bounds__(256) void p3_partition(
    const int* __restrict__ row, const int* __restrict__ col,
    const int* __restrict__ pscan, const int* __restrict__ bbase,
    uint2* __restrict__ part)
{
    __shared__ int spre[NBUK];
    __shared__ int cur[NBUK];
    int t = threadIdx.x;
    for (int q = t; q < NBUK; q += 256) {
        spre[q] = bbase[q] + pscan[blockIdx.x * BPAD + q];
        cur[q] = 0;
    }
    __syncthreads();
    int base = blockIdx.x * 1024 + t;
    #pragma unroll
    for (int u = 0; u < 4; ++u) {
        int e = base + u * 256;
        if (e < NE) {
            int c = col[e];
            int b = c >> 8;
            int rk = atomicAdd(&cur[b], 1);
            part[spre[b] + rk] = make_uint2((uint32)row[e], (uint32)c);
        }
    }
}

// P4: per bucket (256 nodes): LDS count -> scan -> row_ptr/dis/csr_src
__global__ __launch_bounds__(256) void p4_csr(
    const uint2* __restrict__ part, const int* __restrict__ bbase,
    int* __restrict__ row_ptr, float* __restrict__ dis,
    int* __restrict__ csr_src)
{
    __shared__ int cnt[256];
    __shared__ int s[256];
    __shared__ int sexcl[256];
    __shared__ int cur[256];
    int b = blockIdx.x, t = threadIdx.x;
    int base = bbase[b];
    int ecnt = bbase[b + 1] - base;
    int n0 = b << 8;
    cnt[t] = 0;
    cur[t] = 0;
    __syncthreads();
    for (int i = t; i < ecnt; i += 256)
        atomicAdd(&cnt[part[base + i].y - n0], 1);
    __syncthreads();
    int v = cnt[t];
    s[t] = v;
    __syncthreads();
    for (int off = 1; off < 256; off <<= 1) {
        int u = (t >= off) ? s[t - off] : 0;
        __syncthreads();
        s[t] += u;
        __syncthreads();
    }
    sexcl[t] = s[t] - v;
    int node = n0 + t;
    if (node < NN) {
        row_ptr[node] = base + s[t] - v;
        dis[node] = rsqrtf((float)(v + 1));   // +1 self loop
    }
    if (b == 0 && t == 0) row_ptr[NN] = NE;
    __syncthreads();
    for (int i = t; i < ecnt; i += 256) {
        uint2 p = part[base + i];
        int li = (int)p.y - n0;
        int rk = atomicAdd(&cur[li], 1);
        csr_src[base + sexcl[li] + rk] = (int)p.x;
    }
}

// out[i] = bf16( relu( dis[i] * ( mm[i] + sum_e mm[src_e] ) ) ), one wave/node.
__global__ __launch_bounds__(256) void agg_relu(
    const u16* __restrict__ mm, const int* __restrict__ row_ptr,
    const int* __restrict__ csr_src,
    const float* __restrict__ dis, u16* __restrict__ out)
{
    int node = blockIdx.x * 4 + (threadIdx.x >> 6);
    if (node >= NN) return;
    uint32 lane = threadIdx.x & 63;
    const uint32* mv = (const uint32*)mm;
    uint32 self = mv[(uint32)node * 64u + lane];
    f32x2 acc2;
    acc2.x = bflo(self);
    acc2.y = bfhi(self);
    int e0 = row_ptr[node], e1 = row_ptr[node + 1];

    int e = e0;
    for (; e + 16 <= e1; e += 16) {
        uint32 ss[16];
        #pragma unroll
        for (int u = 0; u < 16; ++u) ss[u] = (uint32)csr_src[e + u];
        uint32 vv[16];
        #pragma unroll
        for (int u = 0; u < 16; ++u)
            vv[u] = mv[ss[u] * 64u + lane];
        #pragma unroll
        for (int u = 0; u < 16; ++u) {
            f32x2 tt;
            tt.x = bflo(vv[u]);
            tt.y = bfhi(vv[u]);
            asm("v_pk_add_f32 %0, %0, %1" : "+v"(acc2) : "v"(tt));
        }
    }
    float accx = acc2.x, accy = acc2.y;
    int rem = e1 - e;
    if (rem > 8) {          // 9..15: one masked 16-wide
        uint32 ss[16];
        float mk[16];
        #pragma unroll
        for (int u = 0; u < 16; ++u) {
            int idx = e + u;
            ss[u] = (uint32)csr_src[min(idx, e1 - 1)];
            mk[u] = (idx < e1) ? 1.f : 0.f;
        }
        uint32 vv[16];
        #pragma unroll
        for (int u = 0; u < 16; ++u)
            vv[u] = mv[ss[u] * 64u + lane];
        #pragma unroll
        for (int u = 0; u < 16; ++u) {
            accx = fmaf(mk[u], bflo(vv[u]), accx);
            accy = fmaf(mk[u], bfhi(vv[u]), accy);
        }
    } else if (rem > 0) {   // 1..8: one masked 8-wide
        uint32 ss[8];
        float mk[8];
        #pragma unroll
        for (int u = 0; u < 8; ++u) {
            int idx = e + u;
            ss[u] = (uint32)csr_src[min(idx, e1 - 1)];
            mk[u] = (idx < e1) ? 1.f : 0.f;
        }
        uint32 vv[8];
        #pragma unroll
        for (int u = 0; u < 8; ++u)
            vv[u] = mv[ss[u] * 64u + lane];
        #pragma unroll
        for (int u = 0; u < 8; ++u) {
            accx = fmaf(mk[u], bflo(vv[u]), accx);
            accy = fmaf(mk[u], bfhi(vv[u]), accy);
        }
    }

    float d = dis[node];
    uint32 po = (uint32)f2bf(fmaxf(d * accx, 0.f))
              | ((uint32)f2bf(fmaxf(d * accy, 0.f)) << 16);
    ((uint32*)out)[(uint32)node * 64u + lane] = po;
}

// pooled[batch[n]][aoff + 2c..2c+1] += h[n][2c..2c+1]; 64 threads, uint32 loads
__global__ __launch_bounds__(64) void pool_add(
    const u16* __restrict__ h, const int* __restrict__ batch,
    float* __restrict__ pooled, int aoff)
{
    int c2 = threadIdx.x;                 // col pair
    const uint32* hv = (const uint32*)h;
    int n0 = blockIdx.x * 64;
    int nend = min(n0 + 64, NN);
    int cur = batch[n0];
    float ax = 0.f, ay = 0.f;
    for (int n = n0; n < nend; ++n) {
        int g = batch[n];
        if (g != cur) {
            atomicAdd(&pooled[(size_t)cur * 256 + aoff + 2 * c2], ax);
            atomicAdd(&pooled[(size_t)cur * 256 + aoff + 2 * c2 + 1], ay);
            ax = 0.f; ay = 0.f;
            cur = g;
        }
        uint32 v = hv[(size_t)n * 64 + c2];
        ax += bflo(v);
        ay += bfhi(v);
    }
    atomicAdd(&pooled[(size_t)cur * 256 + aoff + 2 * c2], ax);
    atomicAdd(&pooled[(size_t)cur * 256 + aoff + 2 * c2 + 1], ay);
}

// out[g] = relu(pooled[g] @ w1 + b1) @ w2 + b2
__global__ __launch_bounds__(128) void head(
    const float* __restrict__ pooled,
    const float* __restrict__ w1, const float* __restrict__ b1,
    const float* __restrict__ w2, const float* __restrict__ b2,
    float* __restrict__ out)
{
    __shared__ float sp[256];
    __shared__ float sg[128];
    int g = blockIdx.x, t = threadIdx.x;
    sp[t] = pooled[(size_t)g * 256 + t];
    sp[t + 128] = pooled[(size_t)g * 256 + 128 + t];
    __syncthreads();
    float acc = b1[t];
    #pragma unroll 8
    for (int k = 0; k < 256; ++k) acc = fmaf(sp[k], w1[k * 128 + t], acc);
    sg[t] = fmaxf(acc, 0.f) * w2[t];
    __syncthreads();
    for (int s2 = 64; s2 > 0; s2 >>= 1) {
        if (t < s2) sg[t] += sg[t + s2];
        __syncthreads();
    }
    if (t == 0) out[g] = sg[0] + b2[0];
}

extern "C" void kernel_launch(void* const* d_in, const int* in_sizes, int n_in,
                              void* d_out, int out_size, void* d_ws, size_t ws_size,
                              hipStream_t stream) {
    const float* x      = (const float*)d_in[0];
    const int*   ei     = (const int*)d_in[1];
    const int*   batch  = (const int*)d_in[2];
    const float* lin0_w = (const float*)d_in[3];
    const float* lin0_b = (const float*)d_in[4];
    const float* conv_w = (const float*)d_in[5];
    const float* lin1_w = (const float*)d_in[6];
    const float* lin1_b = (const float*)d_in[7];
    const float* lin2_w = (const float*)d_in[8];
    const float* lin2_b = (const float*)d_in[9];
    float* out = (float*)d_out;

    const size_t NB = (size_t)NN * HD;
    float* x0f    = (float*)d_ws;              // first half: x0 bf16; second: xbf
    float* bufA   = x0f + NB;                  // mm (bf16); also part[]
    float* bufB   = bufA + NB;                 // h (bf16)
    float* pooled = bufB + NB;
    int*   row_ptr = (int*)(pooled + (size_t)NG * 256);
    float* dis     = (float*)(row_ptr + NN + 1);
    int*   csr_src = (int*)(dis + NN);
    u16*   wt      = (u16*)(csr_src + NE);     // 7 x 128 x 128 bf16 = 224 KB
    int*   bcnt    = (int*)(wt + 7 * HD * HD); // EB x BPAD = 2.5 MB
    int*   pscan   = bcnt + EB * BPAD;         // EB x BPAD = 2.5 MB
    int*   btot    = pscan + EB * BPAD;        // NBUK
    int*   bbase   = btot + BPAD;              // NBUK + 1

    u16* x0bf    = (u16*)x0f;                  // NB bf16 = 25.6 MB
    u16* xbf     = (u16*)(x0f + NB / 2);       // x as bf16, 25.6 MB
    u16* mm      = (u16*)bufA;
    u16* hbuf    = (u16*)bufB;
    uint2* part  = (uint2*)bufA;   // dead before first conv gemm writes mm

    const int GEMM_BLOCKS = (((NN + 63) / 64) * 2 + 3) / 4;   // 782

    hipMemsetAsync(pooled, 0, (size_t)NG * 256 * sizeof(float), stream);

    to_bf16<<<NN * HD / 8 / 256, 256, 0, stream>>>(x, xbf);
    wt_prep<<<NADJ * NLAY + 1, 256, 0, stream>>>(conv_w, lin0_w, wt);

    // x0 = bf16(relu(x @ lin0_w + lin0_b))   via MFMA
    gemm_mfma<<<GEMM_BLOCKS, 256, 0, stream>>>(
        xbf, wt + 6 * HD * HD, x0bf, nullptr, lin0_b, 1);

    for (int a = 0; a < NADJ; ++a) {
        const int* row = ei + (size_t)a * 2 * NE;
        const int* col = row + NE;

        p1_count<<<EB, 256, 0, stream>>>(col, bcnt);
        p2a_scanblocks<<<NBUK, 256, 0, stream>>>(bcnt, pscan, btot);
        p2b_scanbuckets<<<1, 512, 0, stream>>>(btot, bbase);
        p3_partition<<<EB, 256, 0, stream>>>(row, col, pscan, bbase, part);
        p4_csr<<<NBUK, 256, 0, stream>>>(part, bbase, row_ptr, dis, csr_src);

        const u16* h = x0bf;
        for (int l = 0; l < NLAY; ++l) {
            const u16* Wt = wt + ((size_t)a * NLAY + l) * HD * HD;
            gemm_mfma<<<GEMM_BLOCKS, 256, 0, stream>>>(h, Wt, mm, dis,
                                                       nullptr, 0);
            agg_relu<<<(NN + 3) / 4, 256, 0, stream>>>(mm, row_ptr, csr_src,
                                                       dis, hbuf);
            h = hbuf;
        }
        pool_add<<<(NN + 63) / 64, 64, 0, stream>>>(hbuf, batch, pooled, a * HD);
    }

    head<<<NG, 128, 0, stream>>>(pooled, lin1_w, lin1_b, lin2_w, lin2_b, out);
}

// Round 13
// 738.130 us; speedup vs baseline: 1.2144x; 1.0094x over previous
//
#include <hip/hip_runtime.h>

#define NN 100000
#define NE 1600000
#define NADJ 2
#define NLAY 3
#define HD 128
#define NG 1024

#define EB   1563    // edge blocks of 1024
#define NBUK 391     // col buckets of 256 nodes
#define BPAD 400     // padded bucket stride

typedef unsigned int uint32;
typedef unsigned short u16;

typedef __attribute__((ext_vector_type(8))) short bfrag8;   // 8 bf16 (4 VGPR)
typedef __attribute__((ext_vector_type(4))) float f32x4;
typedef __attribute__((ext_vector_type(2))) float f32x2;

__device__ __forceinline__ u16 f2bf(float f) {   // RNE pack
    uint32 u = __float_as_uint(f);
    u += 0x7FFFu + ((u >> 16) & 1u);
    return (u16)(u >> 16);
}
__device__ __forceinline__ float bflo(uint32 u) { return __uint_as_float(u << 16); }
__device__ __forceinline__ float bfhi(uint32 u) { return __uint_as_float(u & 0xFFFF0000u); }

// x (fp32) -> bf16, 8 elems/thread; grid covers NN*HD/8 EXACTLY (6250 blocks)
__global__ __launch_bounds__(256) void to_bf16(const float* __restrict__ in,
                                               u16* __restrict__ o) {
    int i = blockIdx.x * 256 + threadIdx.x;
    float4 a = ((const float4*)in)[i * 2];
    float4 b = ((const float4*)in)[i * 2 + 1];
    uint4 v;
    v.x = (uint32)f2bf(a.x) | ((uint32)f2bf(a.y) << 16);
    v.y = (uint32)f2bf(a.z) | ((uint32)f2bf(a.w) << 16);
    v.z = (uint32)f2bf(b.x) | ((uint32)f2bf(b.y) << 16);
    v.w = (uint32)f2bf(b.z) | ((uint32)f2bf(b.w) << 16);
    ((uint4*)o)[i] = v;
}

// one-time: wt[b][n][k] = bf16(W_b[k][n]); b in [0,6) -> conv, b==6 -> lin0_w
__global__ void wt_prep(const float* __restrict__ conv_w,
                        const float* __restrict__ lin0_w, u16* __restrict__ wt) {
    const float* W = (blockIdx.x < 6) ? conv_w + (size_t)blockIdx.x * HD * HD
                                      : lin0_w;
    u16* o = wt + (size_t)blockIdx.x * HD * HD;
    for (int i = 0; i < 64; ++i) {
        int idx = i * 256 + threadIdx.x;
        int n = idx >> 7, k = idx & 127;
        o[idx] = f2bf(W[k * 128 + n]);
    }
}

// ---------------- MFMA GEMM, LDS-free: out = bf16( post( A @ W ) ) ----------
__global__ __launch_bounds__(256) void gemm_mfma(
    const u16* __restrict__ Abf, const u16* __restrict__ Wt,
    u16* __restrict__ outbf, const float* __restrict__ dis,
    const float* __restrict__ bias, int relu)
{
    const int wid = blockIdx.x * 4 + (threadIdx.x >> 6);
    const int lane = threadIdx.x & 63;
    const int row0 = (wid >> 1) * 64;
    if (row0 >= NN) return;
    const int wc = (wid & 1) * 64;
    const int lr = lane & 15, kg = lane >> 4;

    bfrag8 b[4][4];
    #pragma unroll
    for (int ks = 0; ks < 4; ++ks)
        #pragma unroll
        for (int j = 0; j < 4; ++j)
            b[ks][j] = *(const bfrag8*)&Wt[(size_t)(wc + j * 16 + lr) * 128
                                           + (ks * 4 + kg) * 8];

    const f32x4 z = {0.f, 0.f, 0.f, 0.f};
    f32x4 acc[4][4];
    #pragma unroll
    for (int i = 0; i < 4; ++i)
        #pragma unroll
        for (int j = 0; j < 4; ++j) acc[i][j] = z;

    #pragma unroll
    for (int ks = 0; ks < 4; ++ks) {          // K = 4 x 32
        bfrag8 a[4];
        #pragma unroll
        for (int i = 0; i < 4; ++i) {
            int r = min(row0 + i * 16 + lr, NN - 1);   // tail clamp
            a[i] = *(const bfrag8*)&Abf[(size_t)r * 128 + (ks * 4 + kg) * 8];
        }
        #pragma unroll
        for (int i = 0; i < 4; ++i)
            #pragma unroll
            for (int j = 0; j < 4; ++j)
                acc[i][j] = __builtin_amdgcn_mfma_f32_16x16x32_bf16(
                    a[i], b[ks][j], acc[i][j], 0, 0, 0);
    }

    // C/D: col = lane&15, row = (lane>>4)*4 + reg   [m89-verified]
    #pragma unroll
    for (int i = 0; i < 4; ++i) {
        #pragma unroll
        for (int r = 0; r < 4; ++r) {
            int grow = row0 + i * 16 + kg * 4 + r;
            if (grow < NN) {
                float ds = dis ? dis[grow] : 1.f;
                #pragma unroll
                for (int j = 0; j < 4; ++j) {
                    int gcol = wc + j * 16 + lr;
                    float o = acc[i][j][r] * ds;
                    if (bias) o += bias[gcol];
                    if (relu) o = fmaxf(o, 0.f);
                    outbf[(size_t)grow * 128 + gcol] = f2bf(o);
                }
            }
        }
    }
}

// ============ atomic-free CSR build: two-level counting sort ============

// P1: per-block LDS histogram over col buckets (col>>8)
__global__ __launch_bounds__(256) void p1_count(
    const int* __restrict__ col, int* __restrict__ bcnt)
{
    __shared__ int h[NBUK];
    int t = threadIdx.x;
    for (int q = t; q < NBUK; q += 256) h[q] = 0;
    __syncthreads();
    int base = blockIdx.x * 1024 + t;
    #pragma unroll
    for (int u = 0; u < 4; ++u) {
        int e = base + u * 256;
        if (e < NE) atomicAdd(&h[col[e] >> 8], 1);
    }
    __syncthreads();
    for (int q = t; q < NBUK; q += 256)
        bcnt[blockIdx.x * BPAD + q] = h[q];
}

// P2a: per bucket, exclusive scan over the EB block-counts + bucket total
__global__ __launch_bounds__(256) void p2a_scanblocks(
    const int* __restrict__ bcnt, int* __restrict__ pscan,
    int* __restrict__ btot)
{
    __shared__ int s[256];
    int b = blockIdx.x;
    int t = threadIdx.x;
    int v[7];
    int loc = 0;
    #pragma unroll
    for (int j = 0; j < 7; ++j) {
        int idx = t * 7 + j;
        v[j] = (idx < EB) ? bcnt[idx * BPAD + b] : 0;
        loc += v[j];
    }
    s[t] = loc;
    __syncthreads();
    for (int off = 1; off < 256; off <<= 1) {
        int u = (t >= off) ? s[t - off] : 0;
        __syncthreads();
        s[t] += u;
        __syncthreads();
    }
    int pre = s[t] - loc;
    #pragma unroll
    for (int j = 0; j < 7; ++j) {
        int idx = t * 7 + j;
        if (idx < EB) pscan[idx * BPAD + b] = pre;
        pre += v[j];
    }
    if (t == 255) btot[b] = s[255];
}

// P2b: exclusive scan over bucket totals -> bbase[0..NBUK], bbase[NBUK]=NE
__global__ __launch_bounds__(512) void p2b_scanbuckets(
    const int* __restrict__ btot, int* __restrict__ bbase)
{
    __shared__ int s[512];
    int t = threadIdx.x;
    int v = (t < NBUK) ? btot[t] : 0;
    s[t] = v;
    __syncthreads();
    for (int off = 1; off < 512; off <<= 1) {
        int u = (t >= off) ? s[t - off] : 0;
        __syncthreads();
        s[t] += u;
        __syncthreads();
    }
    if (t < NBUK) bbase[t] = s[t] - v;
    if (t == NBUK - 1) bbase[NBUK] = s[t];
}

// P3: partition edges into bucket regions (LDS ranks, plain global stores)
__global__ __launch_bounds__(256) void p3_partition(
    const int* __restrict__ row, const int* __restrict__ col,
    const int* __restrict__ pscan, const int* __restrict__ bbase,
    uint2* __restrict__ part)
{
    __shared__ int spre[NBUK];
    __shared__ int cur[NBUK];
    int t = threadIdx.x;
    for (int q = t; q < NBUK; q += 256) {
        spre[q] = bbase[q] + pscan[blockIdx.x * BPAD + q];
        cur[q] = 0;
    }
    __syncthreads();
    int base = blockIdx.x * 1024 + t;
    #pragma unroll
    for (int u = 0; u < 4; ++u) {
        int e = base + u * 256;
        if (e < NE) {
            int c = col[e];
            int b = c >> 8;
            int rk = atomicAdd(&cur[b], 1);
            part[spre[b] + rk] = make_uint2((uint32)row[e], (uint32)c);
        }
    }
}

// P4: per bucket (256 nodes): LDS count -> scan -> row_ptr/dis/csr_src
__global__ __launch_bounds__(256) void p4_csr(
    const uint2* __restrict__ part, const int* __restrict__ bbase,
    int* __restrict__ row_ptr, float* __restrict__ dis,
    int* __restrict__ csr_src)
{
    __shared__ int cnt[256];
    __shared__ int s[256];
    __shared__ int sexcl[256];
    __shared__ int cur[256];
    int b = blockIdx.x, t = threadIdx.x;
    int base = bbase[b];
    int ecnt = bbase[b + 1] - base;
    int n0 = b << 8;
    cnt[t] = 0;
    cur[t] = 0;
    __syncthreads();
    for (int i = t; i < ecnt; i += 256)
        atomicAdd(&cnt[part[base + i].y - n0], 1);
    __syncthreads();
    int v = cnt[t];
    s[t] = v;
    __syncthreads();
    for (int off = 1; off < 256; off <<= 1) {
        int u = (t >= off) ? s[t - off] : 0;
        __syncthreads();
        s[t] += u;
        __syncthreads();
    }
    sexcl[t] = s[t] - v;
    int node = n0 + t;
    if (node < NN) {
        row_ptr[node] = base + s[t] - v;
        dis[node] = rsqrtf((float)(v + 1));   // +1 self loop
    }
    if (b == 0 && t == 0) row_ptr[NN] = NE;
    __syncthreads();
    for (int i = t; i < ecnt; i += 256) {
        uint2 p = part[base + i];
        int li = (int)p.y - n0;
        int rk = atomicAdd(&cur[li], 1);
        csr_src[base + sexcl[li] + rk] = (int)p.x;
    }
}

// out[i] = bf16( relu( dis[i] * ( mm[i] + sum_e mm[src_e] ) ) ), one wave/node.
// Scalarized index pipeline: lanes 0-15 load 16 indices in ONE coalesced VMEM,
// readlane -> SGPR, row base = scalar math (SALU), gather = saddr-form load
// with lane offset computed once. ~4 VALU/edge vs ~10 before.
__global__ __launch_bounds__(256) void agg_relu(
    const u16* __restrict__ mm, const int* __restrict__ row_ptr,
    const int* __restrict__ csr_src,
    const float* __restrict__ dis, u16* __restrict__ out)
{
    int node = blockIdx.x * 4 + (threadIdx.x >> 6);
    if (node >= NN) return;
    uint32 lane = threadIdx.x & 63;
    const uint32* mv = (const uint32*)mm;
    uint32 self = mv[(uint32)node * 64u + lane];
    f32x2 acc2;
    acc2.x = bflo(self);
    acc2.y = bfhi(self);
    int e0 = row_ptr[node], e1 = row_ptr[node + 1];
    int lan16 = (int)(lane & 15);

    int e = e0;
    for (; e + 16 <= e1; e += 16) {
        uint32 packidx = (uint32)csr_src[e + lan16];   // 16 idx in lanes 0-15
        #pragma unroll
        for (int u = 0; u < 16; ++u) {
            uint32 si = (uint32)__builtin_amdgcn_readlane((int)packidx, u);
            const uint32* srcp = mv + (size_t)si * 64u;   // scalar base (SALU)
            uint32 v = srcp[lane];                        // saddr + lane*4
            f32x2 t;
            t.x = bflo(v);
            t.y = bfhi(v);
            asm("v_pk_add_f32 %0, %0, %1" : "+v"(acc2) : "v"(t));
        }
    }
    int rem = e1 - e;
    if (rem > 8) {          // 9..15: one masked 16-wide
        uint32 packidx = (uint32)csr_src[min(e + lan16, e1 - 1)];
        #pragma unroll
        for (int u = 0; u < 16; ++u) {
            uint32 si = (uint32)__builtin_amdgcn_readlane((int)packidx, u);
            const uint32* srcp = mv + (size_t)si * 64u;
            uint32 v = srcp[lane];
            float mk = (e + u < e1) ? 1.f : 0.f;
            f32x2 t, mkp;
            t.x = bflo(v);
            t.y = bfhi(v);
            mkp.x = mk; mkp.y = mk;
            asm("v_pk_fma_f32 %0, %1, %2, %0" : "+v"(acc2) : "v"(t), "v"(mkp));
        }
    } else if (rem > 0) {   // 1..8: one masked 8-wide
        uint32 packidx = (uint32)csr_src[min(e + (int)(lane & 7), e1 - 1)];
        #pragma unroll
        for (int u = 0; u < 8; ++u) {
            uint32 si = (uint32)__builtin_amdgcn_readlane((int)packidx, u);
            const uint32* srcp = mv + (size_t)si * 64u;
            uint32 v = srcp[lane];
            float mk = (e + u < e1) ? 1.f : 0.f;
            f32x2 t, mkp;
            t.x = bflo(v);
            t.y = bfhi(v);
            mkp.x = mk; mkp.y = mk;
            asm("v_pk_fma_f32 %0, %1, %2, %0" : "+v"(acc2) : "v"(t), "v"(mkp));
        }
    }

    float d = dis[node];
    uint32 po = (uint32)f2bf(fmaxf(d * acc2.x, 0.f))
              | ((uint32)f2bf(fmaxf(d * acc2.y, 0.f)) << 16);
    ((uint32*)out)[(uint32)node * 64u + lane] = po;
}

// pooled[batch[n]][aoff + 2c..2c+1] += h[n][2c..2c+1]; 64 threads, uint32 loads
__global__ __launch_bounds__(64) void pool_add(
    const u16* __restrict__ h, const int* __restrict__ batch,
    float* __restrict__ pooled, int aoff)
{
    int c2 = threadIdx.x;                 // col pair
    const uint32* hv = (const uint32*)h;
    int n0 = blockIdx.x * 64;
    int nend = min(n0 + 64, NN);
    int cur = batch[n0];
    float ax = 0.f, ay = 0.f;
    for (int n = n0; n < nend; ++n) {
        int g = batch[n];
        if (g != cur) {
            atomicAdd(&pooled[(size_t)cur * 256 + aoff + 2 * c2], ax);
            atomicAdd(&pooled[(size_t)cur * 256 + aoff + 2 * c2 + 1], ay);
            ax = 0.f; ay = 0.f;
            cur = g;
        }
        uint32 v = hv[(size_t)n * 64 + c2];
        ax += bflo(v);
        ay += bfhi(v);
    }
    atomicAdd(&pooled[(size_t)cur * 256 + aoff + 2 * c2], ax);
    atomicAdd(&pooled[(size_t)cur * 256 + aoff + 2 * c2 + 1], ay);
}

// out[g] = relu(pooled[g] @ w1 + b1) @ w2 + b2
__global__ __launch_bounds__(128) void head(
    const float* __restrict__ pooled,
    const float* __restrict__ w1, const float* __restrict__ b1,
    const float* __restrict__ w2, const float* __restrict__ b2,
    float* __restrict__ out)
{
    __shared__ float sp[256];
    __shared__ float sg[128];
    int g = blockIdx.x, t = threadIdx.x;
    sp[t] = pooled[(size_t)g * 256 + t];
    sp[t + 128] = pooled[(size_t)g * 256 + 128 + t];
    __syncthreads();
    float acc = b1[t];
    #pragma unroll 8
    for (int k = 0; k < 256; ++k) acc = fmaf(sp[k], w1[k * 128 + t], acc);
    sg[t] = fmaxf(acc, 0.f) * w2[t];
    __syncthreads();
    for (int s2 = 64; s2 > 0; s2 >>= 1) {
        if (t < s2) sg[t] += sg[t + s2];
        __syncthreads();
    }
    if (t == 0) out[g] = sg[0] + b2[0];
}

extern "C" void kernel_launch(void* const* d_in, const int* in_sizes, int n_in,
                              void* d_out, int out_size, void* d_ws, size_t ws_size,
                              hipStream_t stream) {
    const float* x      = (const float*)d_in[0];
    const int*   ei     = (const int*)d_in[1];
    const int*   batch  = (const int*)d_in[2];
    const float* lin0_w = (const float*)d_in[3];
    const float* lin0_b = (const float*)d_in[4];
    const float* conv_w = (const float*)d_in[5];
    const float* lin1_w = (const float*)d_in[6];
    const float* lin1_b = (const float*)d_in[7];
    const float* lin2_w = (const float*)d_in[8];
    const float* lin2_b = (const float*)d_in[9];
    float* out = (float*)d_out;

    const size_t NB = (size_t)NN * HD;
    float* x0f    = (float*)d_ws;              // first half: x0 bf16; second: xbf
    float* bufA   = x0f + NB;                  // mm (bf16); also part[]
    float* bufB   = bufA + NB;                 // h (bf16)
    float* pooled = bufB + NB;
    int*   row_ptr = (int*)(pooled + (size_t)NG * 256);
    float* dis     = (float*)(row_ptr + NN + 1);
    int*   csr_src = (int*)(dis + NN);
    u16*   wt      = (u16*)(csr_src + NE);     // 7 x 128 x 128 bf16 = 224 KB
    int*   bcnt    = (int*)(wt + 7 * HD * HD); // EB x BPAD = 2.5 MB
    int*   pscan   = bcnt + EB * BPAD;         // EB x BPAD = 2.5 MB
    int*   btot    = pscan + EB * BPAD;        // NBUK
    int*   bbase   = btot + BPAD;              // NBUK + 1

    u16* x0bf    = (u16*)x0f;                  // NB bf16 = 25.6 MB
    u16* xbf     = (u16*)(x0f + NB / 2);       // x as bf16, 25.6 MB
    u16* mm      = (u16*)bufA;
    u16* hbuf    = (u16*)bufB;
    uint2* part  = (uint2*)bufA;   // dead before first conv gemm writes mm

    const int GEMM_BLOCKS = (((NN + 63) / 64) * 2 + 3) / 4;   // 782

    hipMemsetAsync(pooled, 0, (size_t)NG * 256 * sizeof(float), stream);

    to_bf16<<<NN * HD / 8 / 256, 256, 0, stream>>>(x, xbf);
    wt_prep<<<NADJ * NLAY + 1, 256, 0, stream>>>(conv_w, lin0_w, wt);

    // x0 = bf16(relu(x @ lin0_w + lin0_b))   via MFMA
    gemm_mfma<<<GEMM_BLOCKS, 256, 0, stream>>>(
        xbf, wt + 6 * HD * HD, x0bf, nullptr, lin0_b, 1);

    for (int a = 0; a < NADJ; ++a) {
        const int* row = ei + (size_t)a * 2 * NE;
        const int* col = row + NE;

        p1_count<<<EB, 256, 0, stream>>>(col, bcnt);
        p2a_scanblocks<<<NBUK, 256, 0, stream>>>(bcnt, pscan, btot);
        p2b_scanbuckets<<<1, 512, 0, stream>>>(btot, bbase);
        p3_partition<<<EB, 256, 0, stream>>>(row, col, pscan, bbase, part);
        p4_csr<<<NBUK, 256, 0, stream>>>(part, bbase, row_ptr, dis, csr_src);

        const u16* h = x0bf;
        for (int l = 0; l < NLAY; ++l) {
            const u16* Wt = wt + ((size_t)a * NLAY + l) * HD * HD;
            gemm_mfma<<<GEMM_BLOCKS, 256, 0, stream>>>(h, Wt, mm, dis,
                                                       nullptr, 0);
            agg_relu<<<(NN + 3) / 4, 256, 0, stream>>>(mm, row_ptr, csr_src,
                                                       dis, hbuf);
            h = hbuf;
        }
        pool_add<<<(NN + 63) / 64, 64, 0, stream>>>(hbuf, batch, pooled, a * HD);
    }

    head<<<NG, 128, 0, stream>>>(pooled, lin1_w, lin1_b, lin2_w, lin2_b, out);
}

// Round 14
// 733.560 us; speedup vs baseline: 1.2220x; 1.0062x over previous
//
#include <hip/hip_runtime.h>

#define NN 100000
#define NE 1600000
#define NADJ 2
#define NLAY 3
#define HD 128
#define NG 1024

#define EB   1563    // edge blocks of 1024
#define NBUK 391     // col buckets of 256 nodes
#define BPAD 400     // padded bucket stride

typedef unsigned int uint32;
typedef unsigned short u16;

typedef __attribute__((ext_vector_type(8))) short bfrag8;   // 8 bf16 (4 VGPR)
typedef __attribute__((ext_vector_type(4))) float f32x4;
typedef __attribute__((ext_vector_type(2))) float f32x2;

__device__ __forceinline__ u16 f2bf(float f) {   // RNE pack
    uint32 u = __float_as_uint(f);
    u += 0x7FFFu + ((u >> 16) & 1u);
    return (u16)(u >> 16);
}
__device__ __forceinline__ float bflo(uint32 u) { return __uint_as_float(u << 16); }
__device__ __forceinline__ float bfhi(uint32 u) { return __uint_as_float(u & 0xFFFF0000u); }

// x (fp32) -> bf16, 8 elems/thread; grid covers NN*HD/8 EXACTLY (6250 blocks)
__global__ __launch_bounds__(256) void to_bf16(const float* __restrict__ in,
                                               u16* __restrict__ o) {
    int i = blockIdx.x * 256 + threadIdx.x;
    float4 a = ((const float4*)in)[i * 2];
    float4 b = ((const float4*)in)[i * 2 + 1];
    uint4 v;
    v.x = (uint32)f2bf(a.x) | ((uint32)f2bf(a.y) << 16);
    v.y = (uint32)f2bf(a.z) | ((uint32)f2bf(a.w) << 16);
    v.z = (uint32)f2bf(b.x) | ((uint32)f2bf(b.y) << 16);
    v.w = (uint32)f2bf(b.z) | ((uint32)f2bf(b.w) << 16);
    ((uint4*)o)[i] = v;
}

// one-time: wt[b][n][k] = bf16(W_b[k][n]); b in [0,6) -> conv, b==6 -> lin0_w
__global__ void wt_prep(const float* __restrict__ conv_w,
                        const float* __restrict__ lin0_w, u16* __restrict__ wt) {
    const float* W = (blockIdx.x < 6) ? conv_w + (size_t)blockIdx.x * HD * HD
                                      : lin0_w;
    u16* o = wt + (size_t)blockIdx.x * HD * HD;
    for (int i = 0; i < 64; ++i) {
        int idx = i * 256 + threadIdx.x;
        int n = idx >> 7, k = idx & 127;
        o[idx] = f2bf(W[k * 128 + n]);
    }
}

// ---------------- MFMA GEMM, LDS-free: out = bf16( post( A @ W ) ) ----------
__global__ __launch_bounds__(256) void gemm_mfma(
    const u16* __restrict__ Abf, const u16* __restrict__ Wt,
    u16* __restrict__ outbf, const float* __restrict__ dis,
    const float* __restrict__ bias, int relu)
{
    const int wid = blockIdx.x * 4 + (threadIdx.x >> 6);
    const int lane = threadIdx.x & 63;
    const int row0 = (wid >> 1) * 64;
    if (row0 >= NN) return;
    const int wc = (wid & 1) * 64;
    const int lr = lane & 15, kg = lane >> 4;

    bfrag8 b[4][4];
    #pragma unroll
    for (int ks = 0; ks < 4; ++ks)
        #pragma unroll
        for (int j = 0; j < 4; ++j)
            b[ks][j] = *(const bfrag8*)&Wt[(size_t)(wc + j * 16 + lr) * 128
                                           + (ks * 4 + kg) * 8];

    const f32x4 z = {0.f, 0.f, 0.f, 0.f};
    f32x4 acc[4][4];
    #pragma unroll
    for (int i = 0; i < 4; ++i)
        #pragma unroll
        for (int j = 0; j < 4; ++j) acc[i][j] = z;

    #pragma unroll
    for (int ks = 0; ks < 4; ++ks) {          // K = 4 x 32
        bfrag8 a[4];
        #pragma unroll
        for (int i = 0; i < 4; ++i) {
            int r = min(row0 + i * 16 + lr, NN - 1);   // tail clamp
            a[i] = *(const bfrag8*)&Abf[(size_t)r * 128 + (ks * 4 + kg) * 8];
        }
        #pragma unroll
        for (int i = 0; i < 4; ++i)
            #pragma unroll
            for (int j = 0; j < 4; ++j)
                acc[i][j] = __builtin_amdgcn_mfma_f32_16x16x32_bf16(
                    a[i], b[ks][j], acc[i][j], 0, 0, 0);
    }

    // C/D: col = lane&15, row = (lane>>4)*4 + reg   [m89-verified]
    #pragma unroll
    for (int i = 0; i < 4; ++i) {
        #pragma unroll
        for (int r = 0; r < 4; ++r) {
            int grow = row0 + i * 16 + kg * 4 + r;
            if (grow < NN) {
                float ds = dis ? dis[grow] : 1.f;
                #pragma unroll
                for (int j = 0; j < 4; ++j) {
                    int gcol = wc + j * 16 + lr;
                    float o = acc[i][j][r] * ds;
                    if (bias) o += bias[gcol];
                    if (relu) o = fmaxf(o, 0.f);
                    outbf[(size_t)grow * 128 + gcol] = f2bf(o);
                }
            }
        }
    }
}

// ============ atomic-free CSR build: two-level counting sort ============

// P1: per-block LDS histogram over col buckets (col>>8)
__global__ __launch_bounds__(256) void p1_count(
    const int* __restrict__ col, int* __restrict__ bcnt)
{
    __shared__ int h[NBUK];
    int t = threadIdx.x;
    for (int q = t; q < NBUK; q += 256) h[q] = 0;
    __syncthreads();
    int base = blockIdx.x * 1024 + t;
    #pragma unroll
    for (int u = 0; u < 4; ++u) {
        int e = base + u * 256;
        if (e < NE) atomicAdd(&h[col[e] >> 8], 1);
    }
    __syncthreads();
    for (int q = t; q < NBUK; q += 256)
        bcnt[blockIdx.x * BPAD + q] = h[q];
}

// P2a: per bucket, exclusive scan over the EB block-counts + bucket total
__global__ __launch_bounds__(256) void p2a_scanblocks(
    const int* __restrict__ bcnt, int* __restrict__ pscan,
    int* __restrict__ btot)
{
    __shared__ int s[256];
    int b = blockIdx.x;
    int t = threadIdx.x;
    int v[7];
    int loc = 0;
    #pragma unroll
    for (int j = 0; j < 7; ++j) {
        int idx = t * 7 + j;
        v[j] = (idx < EB) ? bcnt[idx * BPAD + b] : 0;
        loc += v[j];
    }
    s[t] = loc;
    __syncthreads();
    for (int off = 1; off < 256; off <<= 1) {
        int u = (t >= off) ? s[t - off] : 0;
        __syncthreads();
        s[t] += u;
        __syncthreads();
    }
    int pre = s[t] - loc;
    #pragma unroll
    for (int j = 0; j < 7; ++j) {
        int idx = t * 7 + j;
        if (idx < EB) pscan[idx * BPAD + b] = pre;
        pre += v[j];
    }
    if (t == 255) btot[b] = s[255];
}

// P2b: exclusive scan over bucket totals -> bbase[0..NBUK], bbase[NBUK]=NE
__global__ __launch_bounds__(512) void p2b_scanbuckets(
    const int* __restrict__ btot, int* __restrict__ bbase)
{
    __shared__ int s[512];
    int t = threadIdx.x;
    int v = (t < NBUK) ? btot[t] : 0;
    s[t] = v;
    __syncthreads();
    for (int off = 1; off < 512; off <<= 1) {
        int u = (t >= off) ? s[t - off] : 0;
        __syncthreads();
        s[t] += u;
        __syncthreads();
    }
    if (t < NBUK) bbase[t] = s[t] - v;
    if (t == NBUK - 1) bbase[NBUK] = s[t];
}

// P3: partition edges into bucket regions (LDS ranks, plain global stores)
__global__ __launch_bounds__(256) void p3_partition(
    const int* __restrict__ row, const int* __restrict__ col,
    const int* __restrict__ pscan, const int* __restrict__ bbase,
    uint2* __restrict__ part)
{
    __shared__ int spre[NBUK];
    __shared__ int cur[NBUK];
    int t = threadIdx.x;
    for (int q = t; q < NBUK; q += 256) {
        spre[q] = bbase[q] + pscan[blockIdx.x * BPAD + q];
        cur[q] = 0;
    }
    __syncthreads();
    int base = blockIdx.x * 1024 + t;
    #pragma unroll
    for (int u = 0; u < 4; ++u) {
        int e = base + u * 256;
        if (e < NE) {
            int c = col[e];
            int b = c >> 8;
            int rk = atomicAdd(&cur[b], 1);
            part[spre[b] + rk] = make_uint2((uint32)row[e], (uint32)c);
        }
    }
}

// P4: per bucket (256 nodes): LDS count -> scan -> row_ptr/dis/csr_src
__global__ __launch_bounds__(256) void p4_csr(
    const uint2* __restrict__ part, const int* __restrict__ bbase,
    int* __restrict__ row_ptr, float* __restrict__ dis,
    int* __restrict__ csr_src)
{
    __shared__ int cnt[256];
    __shared__ int s[256];
    __shared__ int sexcl[256];
    __shared__ int cur[256];
    int b = blockIdx.x, t = threadIdx.x;
    int base = bbase[b];
    int ecnt = bbase[b + 1] - base;
    int n0 = b << 8;
    cnt[t] = 0;
    cur[t] = 0;
    __syncthreads();
    for (int i = t; i < ecnt; i += 256)
        atomicAdd(&cnt[part[base + i].y - n0], 1);
    __syncthreads();
    int v = cnt[t];
    s[t] = v;
    __syncthreads();
    for (int off = 1; off < 256; off <<= 1) {
        int u = (t >= off) ? s[t - off] : 0;
        __syncthreads();
        s[t] += u;
        __syncthreads();
    }
    sexcl[t] = s[t] - v;
    int node = n0 + t;
    if (node < NN) {
        row_ptr[node] = base + s[t] - v;
        dis[node] = rsqrtf((float)(v + 1));   // +1 self loop
    }
    if (b == 0 && t == 0) row_ptr[NN] = NE;
    __syncthreads();
    for (int i = t; i < ecnt; i += 256) {
        uint2 p = part[base + i];
        int li = (int)p.y - n0;
        int rk = atomicAdd(&cur[li], 1);
        csr_src[base + sexcl[li] + rk] = (int)p.x;
    }
}

// out[i] = bf16( relu( dis[i] * ( mm[i] + sum_e mm[src_e] ) ) ).
// TWO nodes per wave: independent accumulators, interleaved gather streams ->
// up to 32 outstanding loads (MLP-vs-fabric discriminating experiment).
// Per-node arithmetic order identical to R13 -> bitwise-same output.
__global__ __launch_bounds__(256) void agg_relu(
    const u16* __restrict__ mm, const int* __restrict__ row_ptr,
    const int* __restrict__ csr_src,
    const float* __restrict__ dis, u16* __restrict__ out)
{
    int wid = blockIdx.x * 4 + (threadIdx.x >> 6);
    int nodeA = wid * 2;
    if (nodeA >= NN) return;
    int nodeB = nodeA + 1;                 // NN even -> always valid
    uint32 lane = threadIdx.x & 63;
    const uint32* mv = (const uint32*)mm;
    int lan16 = (int)(lane & 15);

    uint32 selfA = mv[(uint32)nodeA * 64u + lane];
    uint32 selfB = mv[(uint32)nodeB * 64u + lane];
    f32x2 accA, accB;
    accA.x = bflo(selfA); accA.y = bfhi(selfA);
    accB.x = bflo(selfB); accB.y = bfhi(selfB);
    int eA = row_ptr[nodeA], e1A = row_ptr[nodeA + 1];
    int eB = e1A,            e1B = row_ptr[nodeB + 1];   // contiguous CSR

    // joint full chunks: 32 loads in flight
    while (eA + 16 <= e1A && eB + 16 <= e1B) {
        uint32 pA = (uint32)csr_src[eA + lan16];
        uint32 pB = (uint32)csr_src[eB + lan16];
        #pragma unroll
        for (int u = 0; u < 16; ++u) {
            uint32 sA = (uint32)__builtin_amdgcn_readlane((int)pA, u);
            uint32 sB = (uint32)__builtin_amdgcn_readlane((int)pB, u);
            uint32 vA = (mv + (size_t)sA * 64u)[lane];
            uint32 vB = (mv + (size_t)sB * 64u)[lane];
            f32x2 tA, tB;
            tA.x = bflo(vA); tA.y = bfhi(vA);
            tB.x = bflo(vB); tB.y = bfhi(vB);
            asm("v_pk_add_f32 %0, %0, %1" : "+v"(accA) : "v"(tA));
            asm("v_pk_add_f32 %0, %0, %1" : "+v"(accB) : "v"(tB));
        }
        eA += 16; eB += 16;
    }
    // drain leftover full chunks (one stream only)
    for (; eA + 16 <= e1A; eA += 16) {
        uint32 pA = (uint32)csr_src[eA + lan16];
        #pragma unroll
        for (int u = 0; u < 16; ++u) {
            uint32 sA = (uint32)__builtin_amdgcn_readlane((int)pA, u);
            uint32 vA = (mv + (size_t)sA * 64u)[lane];
            f32x2 tA;
            tA.x = bflo(vA); tA.y = bfhi(vA);
            asm("v_pk_add_f32 %0, %0, %1" : "+v"(accA) : "v"(tA));
        }
    }
    for (; eB + 16 <= e1B; eB += 16) {
        uint32 pB = (uint32)csr_src[eB + lan16];
        #pragma unroll
        for (int u = 0; u < 16; ++u) {
            uint32 sB = (uint32)__builtin_amdgcn_readlane((int)pB, u);
            uint32 vB = (mv + (size_t)sB * 64u)[lane];
            f32x2 tB;
            tB.x = bflo(vB); tB.y = bfhi(vB);
            asm("v_pk_add_f32 %0, %0, %1" : "+v"(accB) : "v"(tB));
        }
    }
    int remA = e1A - eA, remB = e1B - eB;
    if ((remA | remB) != 0) {
        if (remA > 0 && remB > 0 && remA <= 8 && remB <= 8) {
            // joint masked 8+8
            uint32 pA = (uint32)csr_src[min(eA + (int)(lane & 7), e1A - 1)];
            uint32 pB = (uint32)csr_src[min(eB + (int)(lane & 7), e1B - 1)];
            #pragma unroll
            for (int u = 0; u < 8; ++u) {
                uint32 sA = (uint32)__builtin_amdgcn_readlane((int)pA, u);
                uint32 sB = (uint32)__builtin_amdgcn_readlane((int)pB, u);
                uint32 vA = (mv + (size_t)sA * 64u)[lane];
                uint32 vB = (mv + (size_t)sB * 64u)[lane];
                float mA = (eA + u < e1A) ? 1.f : 0.f;
                float mB = (eB + u < e1B) ? 1.f : 0.f;
                f32x2 tA, tB, kA, kB;
                tA.x = bflo(vA); tA.y = bfhi(vA); kA.x = mA; kA.y = mA;
                tB.x = bflo(vB); tB.y = bfhi(vB); kB.x = mB; kB.y = mB;
                asm("v_pk_fma_f32 %0, %1, %2, %0" : "+v"(accA) : "v"(tA), "v"(kA));
                asm("v_pk_fma_f32 %0, %1, %2, %0" : "+v"(accB) : "v"(tB), "v"(kB));
            }
        } else {
            // general: masked 16-wide per active stream (interleaved issue)
            uint32 pA = 0, pB = 0;
            if (remA > 0) pA = (uint32)csr_src[min(eA + lan16, e1A - 1)];
            if (remB > 0) pB = (uint32)csr_src[min(eB + lan16, e1B - 1)];
            if (remA > 0 && remB > 0) {
                #pragma unroll
                for (int u = 0; u < 16; ++u) {
                    uint32 sA = (uint32)__builtin_amdgcn_readlane((int)pA, u);
                    uint32 sB = (uint32)__builtin_amdgcn_readlane((int)pB, u);
                    uint32 vA = (mv + (size_t)sA * 64u)[lane];
                    uint32 vB = (mv + (size_t)sB * 64u)[lane];
                    float mA = (eA + u < e1A) ? 1.f : 0.f;
                    float mB = (eB + u < e1B) ? 1.f : 0.f;
                    f32x2 tA, tB, kA, kB;
                    tA.x = bflo(vA); tA.y = bfhi(vA); kA.x = mA; kA.y = mA;
                    tB.x = bflo(vB); tB.y = bfhi(vB); kB.x = mB; kB.y = mB;
                    asm("v_pk_fma_f32 %0, %1, %2, %0" : "+v"(accA) : "v"(tA), "v"(kA));
                    asm("v_pk_fma_f32 %0, %1, %2, %0" : "+v"(accB) : "v"(tB), "v"(kB));
                }
            } else if (remA > 0) {
                #pragma unroll
                for (int u = 0; u < 16; ++u) {
                    uint32 sA = (uint32)__builtin_amdgcn_readlane((int)pA, u);
                    uint32 vA = (mv + (size_t)sA * 64u)[lane];
                    float mA = (eA + u < e1A) ? 1.f : 0.f;
                    f32x2 tA, kA;
                    tA.x = bflo(vA); tA.y = bfhi(vA); kA.x = mA; kA.y = mA;
                    asm("v_pk_fma_f32 %0, %1, %2, %0" : "+v"(accA) : "v"(tA), "v"(kA));
                }
            } else {
                #pragma unroll
                for (int u = 0; u < 16; ++u) {
                    uint32 sB = (uint32)__builtin_amdgcn_readlane((int)pB, u);
                    uint32 vB = (mv + (size_t)sB * 64u)[lane];
                    float mB = (eB + u < e1B) ? 1.f : 0.f;
                    f32x2 tB, kB;
                    tB.x = bflo(vB); tB.y = bfhi(vB); kB.x = mB; kB.y = mB;
                    asm("v_pk_fma_f32 %0, %1, %2, %0" : "+v"(accB) : "v"(tB), "v"(kB));
                }
            }
        }
    }

    float dA = dis[nodeA], dB = dis[nodeB];
    uint32 poA = (uint32)f2bf(fmaxf(dA * accA.x, 0.f))
               | ((uint32)f2bf(fmaxf(dA * accA.y, 0.f)) << 16);
    uint32 poB = (uint32)f2bf(fmaxf(dB * accB.x, 0.f))
               | ((uint32)f2bf(fmaxf(dB * accB.y, 0.f)) << 16);
    ((uint32*)out)[(uint32)nodeA * 64u + lane] = poA;
    ((uint32*)out)[(uint32)nodeB * 64u + lane] = poB;
}

// pooled[batch[n]][aoff + 2c..2c+1] += h[n][2c..2c+1]; 64 threads, uint32 loads
__global__ __launch_bounds__(64) void pool_add(
    const u16* __restrict__ h, const int* __restrict__ batch,
    float* __restrict__ pooled, int aoff)
{
    int c2 = threadIdx.x;                 // col pair
    const uint32* hv = (const uint32*)h;
    int n0 = blockIdx.x * 64;
    int nend = min(n0 + 64, NN);
    int cur = batch[n0];
    float ax = 0.f, ay = 0.f;
    for (int n = n0; n < nend; ++n) {
        int g = batch[n];
        if (g != cur) {
            atomicAdd(&pooled[(size_t)cur * 256 + aoff + 2 * c2], ax);
            atomicAdd(&pooled[(size_t)cur * 256 + aoff + 2 * c2 + 1], ay);
            ax = 0.f; ay = 0.f;
            cur = g;
        }
        uint32 v = hv[(size_t)n * 64 + c2];
        ax += bflo(v);
        ay += bfhi(v);
    }
    atomicAdd(&pooled[(size_t)cur * 256 + aoff + 2 * c2], ax);
    atomicAdd(&pooled[(size_t)cur * 256 + aoff + 2 * c2 + 1], ay);
}

// out[g] = relu(pooled[g] @ w1 + b1) @ w2 + b2
__global__ __launch_bounds__(128) void head(
    const float* __restrict__ pooled,
    const float* __restrict__ w1, const float* __restrict__ b1,
    const float* __restrict__ w2, const float* __restrict__ b2,
    float* __restrict__ out)
{
    __shared__ float sp[256];
    __shared__ float sg[128];
    int g = blockIdx.x, t = threadIdx.x;
    sp[t] = pooled[(size_t)g * 256 + t];
    sp[t + 128] = pooled[(size_t)g * 256 + 128 + t];
    __syncthreads();
    float acc = b1[t];
    #pragma unroll 8
    for (int k = 0; k < 256; ++k) acc = fmaf(sp[k], w1[k * 128 + t], acc);
    sg[t] = fmaxf(acc, 0.f) * w2[t];
    __syncthreads();
    for (int s2 = 64; s2 > 0; s2 >>= 1) {
        if (t < s2) sg[t] += sg[t + s2];
        __syncthreads();
    }
    if (t == 0) out[g] = sg[0] + b2[0];
}

extern "C" void kernel_launch(void* const* d_in, const int* in_sizes, int n_in,
                              void* d_out, int out_size, void* d_ws, size_t ws_size,
                              hipStream_t stream) {
    const float* x      = (const float*)d_in[0];
    const int*   ei     = (const int*)d_in[1];
    const int*   batch  = (const int*)d_in[2];
    const float* lin0_w = (const float*)d_in[3];
    const float* lin0_b = (const float*)d_in[4];
    const float* conv_w = (const float*)d_in[5];
    const float* lin1_w = (const float*)d_in[6];
    const float* lin1_b = (const float*)d_in[7];
    const float* lin2_w = (const float*)d_in[8];
    const float* lin2_b = (const float*)d_in[9];
    float* out = (float*)d_out;

    const size_t NB = (size_t)NN * HD;
    float* x0f    = (float*)d_ws;              // first half: x0 bf16; second: xbf
    float* bufA   = x0f + NB;                  // mm (bf16); also part[]
    float* bufB   = bufA + NB;                 // h (bf16)
    float* pooled = bufB + NB;
    int*   row_ptr = (int*)(pooled + (size_t)NG * 256);
    float* dis     = (float*)(row_ptr + NN + 1);
    int*   csr_src = (int*)(dis + NN);
    u16*   wt      = (u16*)(csr_src + NE);     // 7 x 128 x 128 bf16 = 224 KB
    int*   bcnt    = (int*)(wt + 7 * HD * HD); // EB x BPAD = 2.5 MB
    int*   pscan   = bcnt + EB * BPAD;         // EB x BPAD = 2.5 MB
    int*   btot    = pscan + EB * BPAD;        // NBUK
    int*   bbase   = btot + BPAD;              // NBUK + 1

    u16* x0bf    = (u16*)x0f;                  // NB bf16 = 25.6 MB
    u16* xbf     = (u16*)(x0f + NB / 2);       // x as bf16, 25.6 MB
    u16* mm      = (u16*)bufA;
    u16* hbuf    = (u16*)bufB;
    uint2* part  = (uint2*)bufA;   // dead before first conv gemm writes mm

    const int GEMM_BLOCKS = (((NN + 63) / 64) * 2 + 3) / 4;   // 782

    hipMemsetAsync(pooled, 0, (size_t)NG * 256 * sizeof(float), stream);

    to_bf16<<<NN * HD / 8 / 256, 256, 0, stream>>>(x, xbf);
    wt_prep<<<NADJ * NLAY + 1, 256, 0, stream>>>(conv_w, lin0_w, wt);

    // x0 = bf16(relu(x @ lin0_w + lin0_b))   via MFMA
    gemm_mfma<<<GEMM_BLOCKS, 256, 0, stream>>>(
        xbf, wt + 6 * HD * HD, x0bf, nullptr, lin0_b, 1);

    for (int a = 0; a < NADJ; ++a) {
        const int* row = ei + (size_t)a * 2 * NE;
        const int* col = row + NE;

        p1_count<<<EB, 256, 0, stream>>>(col, bcnt);
        p2a_scanblocks<<<NBUK, 256, 0, stream>>>(bcnt, pscan, btot);
        p2b_scanbuckets<<<1, 512, 0, stream>>>(btot, bbase);
        p3_partition<<<EB, 256, 0, stream>>>(row, col, pscan, bbase, part);
        p4_csr<<<NBUK, 256, 0, stream>>>(part, bbase, row_ptr, dis, csr_src);

        const u16* h = x0bf;
        for (int l = 0; l < NLAY; ++l) {
            const u16* Wt = wt + ((size_t)a * NLAY + l) * HD * HD;
            gemm_mfma<<<GEMM_BLOCKS, 256, 0, stream>>>(h, Wt, mm, dis,
                                                       nullptr, 0);
            agg_relu<<<NN / 8, 256, 0, stream>>>(mm, row_ptr, csr_src,
                                                 dis, hbuf);
            h = hbuf;
        }
        pool_add<<<(NN + 63) / 64, 64, 0, stream>>>(hbuf, batch, pooled, a * HD);
    }

    head<<<NG, 128, 0, stream>>>(pooled, lin1_w, lin1_b, lin2_w, lin2_b, out);
}

// Round 15
// 696.567 us; speedup vs baseline: 1.2869x; 1.0531x over previous
//
#include <hip/hip_runtime.h>

#define NN 100000
#define NE 1600000
#define NADJ 2
#define NLAY 3
#define HD 128
#define NG 1024

#define EB   1563    // edge blocks of 1024
#define NBUK 391     // col buckets of 256 nodes
#define BPAD 400     // padded bucket stride

typedef unsigned int uint32;
typedef unsigned short u16;

typedef __attribute__((ext_vector_type(8))) short bfrag8;   // 8 bf16 (4 VGPR)
typedef __attribute__((ext_vector_type(4))) float f32x4;
typedef __attribute__((ext_vector_type(2))) float f32x2;

__device__ __forceinline__ u16 f2bf(float f) {   // RNE pack
    uint32 u = __float_as_uint(f);
    u += 0x7FFFu + ((u >> 16) & 1u);
    return (u16)(u >> 16);
}
__device__ __forceinline__ float bflo(uint32 u) { return __uint_as_float(u << 16); }
__device__ __forceinline__ float bfhi(uint32 u) { return __uint_as_float(u & 0xFFFF0000u); }

// merged prep: blocks 0..6249 convert x -> bf16 (8 elems/thread, exact);
// blocks 6250..6256 transpose+convert the 7 weight matrices
__global__ __launch_bounds__(256) void prep(
    const float* __restrict__ x, const float* __restrict__ conv_w,
    const float* __restrict__ lin0_w, u16* __restrict__ xbf,
    u16* __restrict__ wt) {
    if (blockIdx.x < 6250) {
        int i = blockIdx.x * 256 + threadIdx.x;
        float4 a = ((const float4*)x)[i * 2];
        float4 b = ((const float4*)x)[i * 2 + 1];
        uint4 v;
        v.x = (uint32)f2bf(a.x) | ((uint32)f2bf(a.y) << 16);
        v.y = (uint32)f2bf(a.z) | ((uint32)f2bf(a.w) << 16);
        v.z = (uint32)f2bf(b.x) | ((uint32)f2bf(b.y) << 16);
        v.w = (uint32)f2bf(b.z) | ((uint32)f2bf(b.w) << 16);
        ((uint4*)xbf)[i] = v;
    } else {
        int bid = blockIdx.x - 6250;
        const float* W = (bid < 6) ? conv_w + (size_t)bid * HD * HD : lin0_w;
        u16* o = wt + (size_t)bid * HD * HD;
        for (int i = 0; i < 64; ++i) {
            int idx = i * 256 + threadIdx.x;
            int n = idx >> 7, k = idx & 127;
            o[idx] = f2bf(W[k * 128 + n]);
        }
    }
}

// ---------------- MFMA GEMM, LDS-free, swapped operands ----------------
// out = bf16( post( A @ W ) ).  mfma(Wt_frag, h_frag): C/D col=lane&15 -> h row,
// row=kg*4+reg -> out col => each f32x4 holds 4 CONSECUTIVE out cols ->
// one uint2 packed store (64->16 store insts/thread vs unswapped).
__global__ __launch_bounds__(256) void gemm_mfma(
    const u16* __restrict__ Abf, const u16* __restrict__ Wt,
    u16* __restrict__ outbf, const float* __restrict__ dis,
    const float* __restrict__ bias, int relu)
{
    const int wid = blockIdx.x * 4 + (threadIdx.x >> 6);
    const int lane = threadIdx.x & 63;
    const int row0 = (wid >> 1) * 64;
    if (row0 >= NN) return;
    const int wc = (wid & 1) * 64;
    const int lr = lane & 15, kg = lane >> 4;

    // "A" operand = Wt fragments (M dim = out cols)
    bfrag8 a[4][4];   // [ks][i]
    #pragma unroll
    for (int ks = 0; ks < 4; ++ks)
        #pragma unroll
        for (int i = 0; i < 4; ++i)
            a[ks][i] = *(const bfrag8*)&Wt[(size_t)(wc + i * 16 + lr) * 128
                                           + (ks * 4 + kg) * 8];

    const f32x4 z = {0.f, 0.f, 0.f, 0.f};
    f32x4 acc[4][4];   // [j=row-tile][i=col-tile]
    #pragma unroll
    for (int j = 0; j < 4; ++j)
        #pragma unroll
        for (int i = 0; i < 4; ++i) acc[j][i] = z;

    #pragma unroll
    for (int ks = 0; ks < 4; ++ks) {          // K = 4 x 32
        bfrag8 b[4];
        #pragma unroll
        for (int j = 0; j < 4; ++j) {
            int r = min(row0 + j * 16 + lr, NN - 1);   // tail clamp
            b[j] = *(const bfrag8*)&Abf[(size_t)r * 128 + (ks * 4 + kg) * 8];
        }
        #pragma unroll
        for (int j = 0; j < 4; ++j)
            #pragma unroll
            for (int i = 0; i < 4; ++i)
                acc[j][i] = __builtin_amdgcn_mfma_f32_16x16x32_bf16(
                    a[ks][i], b[j], acc[j][i], 0, 0, 0);
    }

    #pragma unroll
    for (int j = 0; j < 4; ++j) {
        int m = row0 + j * 16 + lr;
        if (m < NN) {
            float ds = dis ? dis[m] : 1.f;
            #pragma unroll
            for (int i = 0; i < 4; ++i) {
                int colb = wc + i * 16 + kg * 4;
                float4 bb = make_float4(0.f, 0.f, 0.f, 0.f);
                if (bias) bb = *(const float4*)&bias[colb];
                float v0 = acc[j][i][0] * ds + bb.x;
                float v1 = acc[j][i][1] * ds + bb.y;
                float v2 = acc[j][i][2] * ds + bb.z;
                float v3 = acc[j][i][3] * ds + bb.w;
                if (relu) {
                    v0 = fmaxf(v0, 0.f); v1 = fmaxf(v1, 0.f);
                    v2 = fmaxf(v2, 0.f); v3 = fmaxf(v3, 0.f);
                }
                uint2 pk;
                pk.x = (uint32)f2bf(v0) | ((uint32)f2bf(v1) << 16);
                pk.y = (uint32)f2bf(v2) | ((uint32)f2bf(v3) << 16);
                *(uint2*)&outbf[(size_t)m * 128 + colb] = pk;
            }
        }
    }
}

// ======== atomic-free CSR build, both adjacencies batched per launch ========

// P1: per-block LDS histogram over col buckets (col>>8)
__global__ __launch_bounds__(256) void p1_count(
    const int* __restrict__ ei, int* __restrict__ bcnt)
{
    __shared__ int h[NBUK];
    int aa = blockIdx.x >= EB ? 1 : 0;
    int blk = blockIdx.x - aa * EB;
    const int* col = ei + (size_t)aa * 2 * NE + NE;
    int* bc = bcnt + (size_t)aa * EB * BPAD;
    int t = threadIdx.x;
    for (int q = t; q < NBUK; q += 256) h[q] = 0;
    __syncthreads();
    int base = blk * 1024 + t;
    #pragma unroll
    for (int u = 0; u < 4; ++u) {
        int e = base + u * 256;
        if (e < NE) atomicAdd(&h[col[e] >> 8], 1);
    }
    __syncthreads();
    for (int q = t; q < NBUK; q += 256)
        bc[blk * BPAD + q] = h[q];
}

// P2a: per bucket, exclusive scan over the EB block-counts + bucket total
__global__ __launch_bounds__(256) void p2a_scanblocks(
    const int* __restrict__ bcnt, int* __restrict__ pscan,
    int* __restrict__ btot)
{
    __shared__ int s[256];
    int aa = blockIdx.x >= NBUK ? 1 : 0;
    int b = blockIdx.x - aa * NBUK;
    const int* bc = bcnt + (size_t)aa * EB * BPAD;
    int* ps = pscan + (size_t)aa * EB * BPAD;
    int* bt = btot + aa * BPAD;
    int t = threadIdx.x;
    int v[7];
    int loc = 0;
    #pragma unroll
    for (int j = 0; j < 7; ++j) {
        int idx = t * 7 + j;
        v[j] = (idx < EB) ? bc[idx * BPAD + b] : 0;
        loc += v[j];
    }
    s[t] = loc;
    __syncthreads();
    for (int off = 1; off < 256; off <<= 1) {
        int u = (t >= off) ? s[t - off] : 0;
        __syncthreads();
        s[t] += u;
        __syncthreads();
    }
    int pre = s[t] - loc;
    #pragma unroll
    for (int j = 0; j < 7; ++j) {
        int idx = t * 7 + j;
        if (idx < EB) ps[idx * BPAD + b] = pre;
        pre += v[j];
    }
    if (t == 255) bt[b] = s[255];
}

// P2b: exclusive scan over bucket totals -> bbase[0..NBUK], bbase[NBUK]=NE
__global__ __launch_bounds__(512) void p2b_scanbuckets(
    const int* __restrict__ btot, int* __restrict__ bbase)
{
    __shared__ int s[512];
    int aa = blockIdx.x;
    const int* bt = btot + aa * BPAD;
    int* bb = bbase + aa * (NBUK + 1);
    int t = threadIdx.x;
    int v = (t < NBUK) ? bt[t] : 0;
    s[t] = v;
    __syncthreads();
    for (int off = 1; off < 512; off <<= 1) {
        int u = (t >= off) ? s[t - off] : 0;
        __syncthreads();
        s[t] += u;
        __syncthreads();
    }
    if (t < NBUK) bb[t] = s[t] - v;
    if (t == NBUK - 1) bb[NBUK] = s[t];
}

// P3: partition edges into bucket regions (LDS ranks, plain global stores)
__global__ __launch_bounds__(256) void p3_partition(
    const int* __restrict__ ei, const int* __restrict__ pscan,
    const int* __restrict__ bbase, uint2* __restrict__ part)
{
    __shared__ int spre[NBUK];
    __shared__ int cur[NBUK];
    int aa = blockIdx.x >= EB ? 1 : 0;
    int blk = blockIdx.x - aa * EB;
    const int* row = ei + (size_t)aa * 2 * NE;
    const int* col = row + NE;
    const int* ps = pscan + (size_t)aa * EB * BPAD;
    const int* bb = bbase + aa * (NBUK + 1);
    uint2* pt = part + (size_t)aa * NE;
    int t = threadIdx.x;
    for (int q = t; q < NBUK; q += 256) {
        spre[q] = bb[q] + ps[blk * BPAD + q];
        cur[q] = 0;
    }
    __syncthreads();
    int base = blk * 1024 + t;
    #pragma unroll
    for (int u = 0; u < 4; ++u) {
        int e = base + u * 256;
        if (e < NE) {
            int c = col[e];
            int b = c >> 8;
            int rk = atomicAdd(&cur[b], 1);
            pt[spre[b] + rk] = make_uint2((uint32)row[e], (uint32)c);
        }
    }
}

// P4: per bucket (256 nodes): LDS count -> scan -> row_ptr/dis/csr_src
__global__ __launch_bounds__(256) void p4_csr(
    const uint2* __restrict__ part, const int* __restrict__ bbase,
    int* __restrict__ row_ptr, float* __restrict__ dis,
    int* __restrict__ csr_src)
{
    __shared__ int cnt[256];
    __shared__ int s[256];
    __shared__ int sexcl[256];
    __shared__ int cur[256];
    int aa = blockIdx.x >= NBUK ? 1 : 0;
    int b = blockIdx.x - aa * NBUK;
    const uint2* pt = part + (size_t)aa * NE;
    const int* bb = bbase + aa * (NBUK + 1);
    int* rp = row_ptr + (size_t)aa * (NN + 1);
    float* ds = dis + (size_t)aa * NN;
    int* cs = csr_src + (size_t)aa * NE;
    int t = threadIdx.x;
    int base = bb[b];
    int ecnt = bb[b + 1] - base;
    int n0 = b << 8;
    cnt[t] = 0;
    cur[t] = 0;
    __syncthreads();
    for (int i = t; i < ecnt; i += 256)
        atomicAdd(&cnt[pt[base + i].y - n0], 1);
    __syncthreads();
    int v = cnt[t];
    s[t] = v;
    __syncthreads();
    for (int off = 1; off < 256; off <<= 1) {
        int u = (t >= off) ? s[t - off] : 0;
        __syncthreads();
        s[t] += u;
        __syncthreads();
    }
    sexcl[t] = s[t] - v;
    int node = n0 + t;
    if (node < NN) {
        rp[node] = base + s[t] - v;
        ds[node] = rsqrtf((float)(v + 1));   // +1 self loop
    }
    if (b == 0 && t == 0) rp[NN] = NE;
    __syncthreads();
    for (int i = t; i < ecnt; i += 256) {
        uint2 p = pt[base + i];
        int li = (int)p.y - n0;
        int rk = atomicAdd(&cur[li], 1);
        cs[base + sexcl[li] + rk] = (int)p.x;
    }
}

// out[i] = bf16( relu( dis[i] * ( mm[i] + sum_e mm[src_e] ) ) ).
// TWO nodes per wave, scalarized index pipeline (R13/R14 structure).
__global__ __launch_bounds__(256) void agg_relu(
    const u16* __restrict__ mm, const int* __restrict__ row_ptr,
    const int* __restrict__ csr_src,
    const float* __restrict__ dis, u16* __restrict__ out)
{
    int wid = blockIdx.x * 4 + (threadIdx.x >> 6);
    int nodeA = wid * 2;
    if (nodeA >= NN) return;
    int nodeB = nodeA + 1;                 // NN even -> always valid
    uint32 lane = threadIdx.x & 63;
    const uint32* mv = (const uint32*)mm;
    int lan16 = (int)(lane & 15);

    uint32 selfA = mv[(uint32)nodeA * 64u + lane];
    uint32 selfB = mv[(uint32)nodeB * 64u + lane];
    f32x2 accA, accB;
    accA.x = bflo(selfA); accA.y = bfhi(selfA);
    accB.x = bflo(selfB); accB.y = bfhi(selfB);
    int eA = row_ptr[nodeA], e1A = row_ptr[nodeA + 1];
    int eB = e1A,            e1B = row_ptr[nodeB + 1];   // contiguous CSR

    while (eA + 16 <= e1A && eB + 16 <= e1B) {
        uint32 pA = (uint32)csr_src[eA + lan16];
        uint32 pB = (uint32)csr_src[eB + lan16];
        #pragma unroll
        for (int u = 0; u < 16; ++u) {
            uint32 sA = (uint32)__builtin_amdgcn_readlane((int)pA, u);
            uint32 sB = (uint32)__builtin_amdgcn_readlane((int)pB, u);
            uint32 vA = (mv + (size_t)sA * 64u)[lane];
            uint32 vB = (mv + (size_t)sB * 64u)[lane];
            f32x2 tA, tB;
            tA.x = bflo(vA); tA.y = bfhi(vA);
            tB.x = bflo(vB); tB.y = bfhi(vB);
            asm("v_pk_add_f32 %0, %0, %1" : "+v"(accA) : "v"(tA));
            asm("v_pk_add_f32 %0, %0, %1" : "+v"(accB) : "v"(tB));
        }
        eA += 16; eB += 16;
    }
    for (; eA + 16 <= e1A; eA += 16) {
        uint32 pA = (uint32)csr_src[eA + lan16];
        #pragma unroll
        for (int u = 0; u < 16; ++u) {
            uint32 sA = (uint32)__builtin_amdgcn_readlane((int)pA, u);
            uint32 vA = (mv + (size_t)sA * 64u)[lane];
            f32x2 tA;
            tA.x = bflo(vA); tA.y = bfhi(vA);
            asm("v_pk_add_f32 %0, %0, %1" : "+v"(accA) : "v"(tA));
        }
    }
    for (; eB + 16 <= e1B; eB += 16) {
        uint32 pB = (uint32)csr_src[eB + lan16];
        #pragma unroll
        for (int u = 0; u < 16; ++u) {
            uint32 sB = (uint32)__builtin_amdgcn_readlane((int)pB, u);
            uint32 vB = (mv + (size_t)sB * 64u)[lane];
            f32x2 tB;
            tB.x = bflo(vB); tB.y = bfhi(vB);
            asm("v_pk_add_f32 %0, %0, %1" : "+v"(accB) : "v"(tB));
        }
    }
    int remA = e1A - eA, remB = e1B - eB;
    if ((remA | remB) != 0) {
        if (remA > 0 && remB > 0 && remA <= 8 && remB <= 8) {
            uint32 pA = (uint32)csr_src[min(eA + (int)(lane & 7), e1A - 1)];
            uint32 pB = (uint32)csr_src[min(eB + (int)(lane & 7), e1B - 1)];
            #pragma unroll
            for (int u = 0; u < 8; ++u) {
                uint32 sA = (uint32)__builtin_amdgcn_readlane((int)pA, u);
                uint32 sB = (uint32)__builtin_amdgcn_readlane((int)pB, u);
                uint32 vA = (mv + (size_t)sA * 64u)[lane];
                uint32 vB = (mv + (size_t)sB * 64u)[lane];
                float mA = (eA + u < e1A) ? 1.f : 0.f;
                float mB = (eB + u < e1B) ? 1.f : 0.f;
                f32x2 tA, tB, kA, kB;
                tA.x = bflo(vA); tA.y = bfhi(vA); kA.x = mA; kA.y = mA;
                tB.x = bflo(vB); tB.y = bfhi(vB); kB.x = mB; kB.y = mB;
                asm("v_pk_fma_f32 %0, %1, %2, %0" : "+v"(accA) : "v"(tA), "v"(kA));
                asm("v_pk_fma_f32 %0, %1, %2, %0" : "+v"(accB) : "v"(tB), "v"(kB));
            }
        } else {
            uint32 pA = 0, pB = 0;
            if (remA > 0) pA = (uint32)csr_src[min(eA + lan16, e1A - 1)];
            if (remB > 0) pB = (uint32)csr_src[min(eB + lan16, e1B - 1)];
            if (remA > 0 && remB > 0) {
                #pragma unroll
                for (int u = 0; u < 16; ++u) {
                    uint32 sA = (uint32)__builtin_amdgcn_readlane((int)pA, u);
                    uint32 sB = (uint32)__builtin_amdgcn_readlane((int)pB, u);
                    uint32 vA = (mv + (size_t)sA * 64u)[lane];
                    uint32 vB = (mv + (size_t)sB * 64u)[lane];
                    float mA = (eA + u < e1A) ? 1.f : 0.f;
                    float mB = (eB + u < e1B) ? 1.f : 0.f;
                    f32x2 tA, tB, kA, kB;
                    tA.x = bflo(vA); tA.y = bfhi(vA); kA.x = mA; kA.y = mA;
                    tB.x = bflo(vB); tB.y = bfhi(vB); kB.x = mB; kB.y = mB;
                    asm("v_pk_fma_f32 %0, %1, %2, %0" : "+v"(accA) : "v"(tA), "v"(kA));
                    asm("v_pk_fma_f32 %0, %1, %2, %0" : "+v"(accB) : "v"(tB), "v"(kB));
                }
            } else if (remA > 0) {
                #pragma unroll
                for (int u = 0; u < 16; ++u) {
                    uint32 sA = (uint32)__builtin_amdgcn_readlane((int)pA, u);
                    uint32 vA = (mv + (size_t)sA * 64u)[lane];
                    float mA = (eA + u < e1A) ? 1.f : 0.f;
                    f32x2 tA, kA;
                    tA.x = bflo(vA); tA.y = bfhi(vA); kA.x = mA; kA.y = mA;
                    asm("v_pk_fma_f32 %0, %1, %2, %0" : "+v"(accA) : "v"(tA), "v"(kA));
                }
            } else {
                #pragma unroll
                for (int u = 0; u < 16; ++u) {
                    uint32 sB = (uint32)__builtin_amdgcn_readlane((int)pB, u);
                    uint32 vB = (mv + (size_t)sB * 64u)[lane];
                    float mB = (eB + u < e1B) ? 1.f : 0.f;
                    f32x2 tB, kB;
                    tB.x = bflo(vB); tB.y = bfhi(vB); kB.x = mB; kB.y = mB;
                    asm("v_pk_fma_f32 %0, %1, %2, %0" : "+v"(accB) : "v"(tB), "v"(kB));
                }
            }
        }
    }

    float dA = dis[nodeA], dB = dis[nodeB];
    uint32 poA = (uint32)f2bf(fmaxf(dA * accA.x, 0.f))
               | ((uint32)f2bf(fmaxf(dA * accA.y, 0.f)) << 16);
    uint32 poB = (uint32)f2bf(fmaxf(dB * accB.x, 0.f))
               | ((uint32)f2bf(fmaxf(dB * accB.y, 0.f)) << 16);
    ((uint32*)out)[(uint32)nodeA * 64u + lane] = poA;
    ((uint32*)out)[(uint32)nodeB * 64u + lane] = poB;
}

// pooled[batch[n]][aoff + 2c..2c+1] += h[n][2c..2c+1]; 64 threads, uint32 loads
__global__ __launch_bounds__(64) void pool_add(
    const u16* __restrict__ h, const int* __restrict__ batch,
    float* __restrict__ pooled, int aoff)
{
    int c2 = threadIdx.x;                 // col pair
    const uint32* hv = (const uint32*)h;
    int n0 = blockIdx.x * 64;
    int nend = min(n0 + 64, NN);
    int cur = batch[n0];
    float ax = 0.f, ay = 0.f;
    for (int n = n0; n < nend; ++n) {
        int g = batch[n];
        if (g != cur) {
            atomicAdd(&pooled[(size_t)cur * 256 + aoff + 2 * c2], ax);
            atomicAdd(&pooled[(size_t)cur * 256 + aoff + 2 * c2 + 1], ay);
            ax = 0.f; ay = 0.f;
            cur = g;
        }
        uint32 v = hv[(size_t)n * 64 + c2];
        ax += bflo(v);
        ay += bfhi(v);
    }
    atomicAdd(&pooled[(size_t)cur * 256 + aoff + 2 * c2], ax);
    atomicAdd(&pooled[(size_t)cur * 256 + aoff + 2 * c2 + 1], ay);
}

// out[g] = relu(pooled[g] @ w1 + b1) @ w2 + b2
__global__ __launch_bounds__(128) void head(
    const float* __restrict__ pooled,
    const float* __restrict__ w1, const float* __restrict__ b1,
    const float* __restrict__ w2, const float* __restrict__ b2,
    float* __restrict__ out)
{
    __shared__ float sp[256];
    __shared__ float sg[128];
    int g = blockIdx.x, t = threadIdx.x;
    sp[t] = pooled[(size_t)g * 256 + t];
    sp[t + 128] = pooled[(size_t)g * 256 + 128 + t];
    __syncthreads();
    float acc = b1[t];
    #pragma unroll 8
    for (int k = 0; k < 256; ++k) acc = fmaf(sp[k], w1[k * 128 + t], acc);
    sg[t] = fmaxf(acc, 0.f) * w2[t];
    __syncthreads();
    for (int s2 = 64; s2 > 0; s2 >>= 1) {
        if (t < s2) sg[t] += sg[t + s2];
        __syncthreads();
    }
    if (t == 0) out[g] = sg[0] + b2[0];
}

extern "C" void kernel_launch(void* const* d_in, const int* in_sizes, int n_in,
                              void* d_out, int out_size, void* d_ws, size_t ws_size,
                              hipStream_t stream) {
    const float* x      = (const float*)d_in[0];
    const int*   ei     = (const int*)d_in[1];
    const int*   batch  = (const int*)d_in[2];
    const float* lin0_w = (const float*)d_in[3];
    const float* lin0_b = (const float*)d_in[4];
    const float* conv_w = (const float*)d_in[5];
    const float* lin1_w = (const float*)d_in[6];
    const float* lin1_b = (const float*)d_in[7];
    const float* lin2_w = (const float*)d_in[8];
    const float* lin2_b = (const float*)d_in[9];
    float* out = (float*)d_out;

    const size_t NB = (size_t)NN * HD;
    float* x0f    = (float*)d_ws;              // x0bf (NB u16) + xbf (NB u16)
    float* bufA   = x0f + NB;                  // mm (NB u16) | part2 (2*NE uint2)
    float* bufB   = bufA + NB;                 // hbuf
    float* pooled = bufB + NB;
    int*   row_ptr2 = (int*)(pooled + (size_t)NG * 256);   // 2*(NN+1)
    float* dis2     = (float*)(row_ptr2 + 2 * (NN + 1));   // 2*NN
    int*   csr2     = (int*)(dis2 + 2 * NN);               // 2*NE
    u16*   wt       = (u16*)(csr2 + 2 * NE);               // 7*HD*HD
    int*   bcnt2    = (int*)(wt + 7 * HD * HD);            // 2*EB*BPAD
    int*   pscan2   = bcnt2 + 2 * EB * BPAD;               // 2*EB*BPAD
    int*   btot2    = pscan2 + 2 * EB * BPAD;              // 2*BPAD
    int*   bbase2   = btot2 + 2 * BPAD;                    // 2*(NBUK+1)

    u16* x0bf    = (u16*)x0f;                  // 25.6 MB
    u16* xbf     = (u16*)(x0f + NB / 2);       // 25.6 MB
    u16* mm      = (u16*)bufA;                 // first half of bufA
    uint2* part2 = (uint2*)(bufA + NB / 2);    // second half (dead once mm live)
    u16* hbuf    = (u16*)bufB;

    const int GEMM_BLOCKS = (((NN + 63) / 64) * 2 + 3) / 4;   // 782

    hipMemsetAsync(pooled, 0, (size_t)NG * 256 * sizeof(float), stream);

    prep<<<6250 + 7, 256, 0, stream>>>(x, conv_w, lin0_w, xbf, wt);

    // CSR build for BOTH adjacencies, batched launches
    p1_count<<<2 * EB, 256, 0, stream>>>(ei, bcnt2);
    p2a_scanblocks<<<2 * NBUK, 256, 0, stream>>>(bcnt2, pscan2, btot2);
    p2b_scanbuckets<<<2, 512, 0, stream>>>(btot2, bbase2);
    p3_partition<<<2 * EB, 256, 0, stream>>>(ei, pscan2, bbase2, part2);
    p4_csr<<<2 * NBUK, 256, 0, stream>>>(part2, bbase2, row_ptr2, dis2, csr2);

    // x0 = bf16(relu(x @ lin0_w + lin0_b))   via MFMA
    gemm_mfma<<<GEMM_BLOCKS, 256, 0, stream>>>(
        xbf, wt + 6 * HD * HD, x0bf, nullptr, lin0_b, 1);

    for (int a = 0; a < NADJ; ++a) {
        const int*   rp = row_ptr2 + (size_t)a * (NN + 1);
        const float* ds = dis2 + (size_t)a * NN;
        const int*   cs = csr2 + (size_t)a * NE;

        const u16* h = x0bf;
        for (int l = 0; l < NLAY; ++l) {
            const u16* Wt = wt + ((size_t)a * NLAY + l) * HD * HD;
            gemm_mfma<<<GEMM_BLOCKS, 256, 0, stream>>>(h, Wt, mm, ds,
                                                       nullptr, 0);
            agg_relu<<<NN / 8, 256, 0, stream>>>(mm, rp, cs, ds, hbuf);
            h = hbuf;
        }
        pool_add<<<(NN + 63) / 64, 64, 0, stream>>>(hbuf, batch, pooled, a * HD);
    }

    head<<<NG, 128, 0, stream>>>(pooled, lin1_w, lin1_b, lin2_w, lin2_b, out);
}

// Round 16
// 619.986 us; speedup vs baseline: 1.4459x; 1.1235x over previous
//
#include <hip/hip_runtime.h>

#define NN 100000
#define NE 1600000
#define NADJ 2
#define NLAY 3
#define HD 128
#define NG 1024

#define EBLK 4096    // edges per partition block
#define EB   391     // ceil(NE/EBLK)
#define NBUK 196     // col buckets of 512 nodes
#define BPAD 200     // padded bucket stride
#define GB   782     // gemm blocks per adjacency
#define AB   12500   // agg blocks per adjacency (NN/8)
#define PB   1563    // pool blocks per adjacency

typedef unsigned int uint32;
typedef unsigned short u16;

typedef __attribute__((ext_vector_type(8))) short bfrag8;   // 8 bf16 (4 VGPR)
typedef __attribute__((ext_vector_type(4))) float f32x4;
typedef __attribute__((ext_vector_type(2))) float f32x2;

__device__ __forceinline__ u16 f2bf(float f) {   // RNE pack
    uint32 u = __float_as_uint(f);
    u += 0x7FFFu + ((u >> 16) & 1u);
    return (u16)(u >> 16);
}
__device__ __forceinline__ float bflo(uint32 u) { return __uint_as_float(u << 16); }
__device__ __forceinline__ float bfhi(uint32 u) { return __uint_as_float(u & 0xFFFF0000u); }

// merged prep: blocks 0..6249 convert x -> bf16; 6250..6256 transpose weights
__global__ __launch_bounds__(256) void prep(
    const float* __restrict__ x, const float* __restrict__ conv_w,
    const float* __restrict__ lin0_w, u16* __restrict__ xbf,
    u16* __restrict__ wt) {
    if (blockIdx.x < 6250) {
        int i = blockIdx.x * 256 + threadIdx.x;
        float4 a = ((const float4*)x)[i * 2];
        float4 b = ((const float4*)x)[i * 2 + 1];
        uint4 v;
        v.x = (uint32)f2bf(a.x) | ((uint32)f2bf(a.y) << 16);
        v.y = (uint32)f2bf(a.z) | ((uint32)f2bf(a.w) << 16);
        v.z = (uint32)f2bf(b.x) | ((uint32)f2bf(b.y) << 16);
        v.w = (uint32)f2bf(b.z) | ((uint32)f2bf(b.w) << 16);
        ((uint4*)xbf)[i] = v;
    } else {
        int bid = blockIdx.x - 6250;
        const float* W = (bid < 6) ? conv_w + (size_t)bid * HD * HD : lin0_w;
        u16* o = wt + (size_t)bid * HD * HD;
        for (int i = 0; i < 64; ++i) {
            int idx = i * 256 + threadIdx.x;
            int n = idx >> 7, k = idx & 127;
            o[idx] = f2bf(W[k * 128 + n]);
        }
    }
}

// ---------------- MFMA GEMM (lin0): swapped operands, packed stores ----------
__global__ __launch_bounds__(256) void gemm_mfma(
    const u16* __restrict__ Abf, const u16* __restrict__ Wt,
    u16* __restrict__ outbf, const float* __restrict__ bias)
{
    const int wid = blockIdx.x * 4 + (threadIdx.x >> 6);
    const int lane = threadIdx.x & 63;
    const int row0 = (wid >> 1) * 64;
    if (row0 >= NN) return;
    const int wc = (wid & 1) * 64;
    const int lr = lane & 15, kg = lane >> 4;

    bfrag8 a[4][4];
    #pragma unroll
    for (int ks = 0; ks < 4; ++ks)
        #pragma unroll
        for (int i = 0; i < 4; ++i)
            a[ks][i] = *(const bfrag8*)&Wt[(size_t)(wc + i * 16 + lr) * 128
                                           + (ks * 4 + kg) * 8];

    const f32x4 z = {0.f, 0.f, 0.f, 0.f};
    f32x4 acc[4][4];
    #pragma unroll
    for (int j = 0; j < 4; ++j)
        #pragma unroll
        for (int i = 0; i < 4; ++i) acc[j][i] = z;

    #pragma unroll
    for (int ks = 0; ks < 4; ++ks) {
        bfrag8 b[4];
        #pragma unroll
        for (int j = 0; j < 4; ++j) {
            int r = min(row0 + j * 16 + lr, NN - 1);
            b[j] = *(const bfrag8*)&Abf[(size_t)r * 128 + (ks * 4 + kg) * 8];
        }
        #pragma unroll
        for (int j = 0; j < 4; ++j)
            #pragma unroll
            for (int i = 0; i < 4; ++i)
                acc[j][i] = __builtin_amdgcn_mfma_f32_16x16x32_bf16(
                    a[ks][i], b[j], acc[j][i], 0, 0, 0);
    }

    #pragma unroll
    for (int j = 0; j < 4; ++j) {
        int m = row0 + j * 16 + lr;
        if (m < NN) {
            #pragma unroll
            for (int i = 0; i < 4; ++i) {
                int colb = wc + i * 16 + kg * 4;
                float4 bb = *(const float4*)&bias[colb];
                float v0 = fmaxf(acc[j][i][0] + bb.x, 0.f);
                float v1 = fmaxf(acc[j][i][1] + bb.y, 0.f);
                float v2 = fmaxf(acc[j][i][2] + bb.z, 0.f);
                float v3 = fmaxf(acc[j][i][3] + bb.w, 0.f);
                uint2 pk;
                pk.x = (uint32)f2bf(v0) | ((uint32)f2bf(v1) << 16);
                pk.y = (uint32)f2bf(v2) | ((uint32)f2bf(v3) << 16);
                *(uint2*)&outbf[(size_t)m * 128 + colb] = pk;
            }
        }
    }
}

// conv GEMM, both adjacencies batched: mm2[aa] = bf16(dis[aa] .* (h[aa] @ W[aa,l]))
__global__ __launch_bounds__(256) void gemm_mfma_b(
    const u16* __restrict__ hbase, int shared, const u16* __restrict__ wt,
    int l, u16* __restrict__ mm2, const float* __restrict__ dis2)
{
    int aa = blockIdx.x >= GB ? 1 : 0;
    int bblk = blockIdx.x - aa * GB;
    const u16* Abf = shared ? hbase : hbase + (size_t)aa * NN * HD;
    const u16* Wt = wt + (size_t)(aa * NLAY + l) * HD * HD;
    u16* outbf = mm2 + (size_t)aa * NN * HD;
    const float* dis = dis2 + (size_t)aa * NN;

    const int wid = bblk * 4 + (threadIdx.x >> 6);
    const int lane = threadIdx.x & 63;
    const int row0 = (wid >> 1) * 64;
    if (row0 >= NN) return;
    const int wc = (wid & 1) * 64;
    const int lr = lane & 15, kg = lane >> 4;

    bfrag8 a[4][4];
    #pragma unroll
    for (int ks = 0; ks < 4; ++ks)
        #pragma unroll
        for (int i = 0; i < 4; ++i)
            a[ks][i] = *(const bfrag8*)&Wt[(size_t)(wc + i * 16 + lr) * 128
                                           + (ks * 4 + kg) * 8];

    const f32x4 z = {0.f, 0.f, 0.f, 0.f};
    f32x4 acc[4][4];
    #pragma unroll
    for (int j = 0; j < 4; ++j)
        #pragma unroll
        for (int i = 0; i < 4; ++i) acc[j][i] = z;

    #pragma unroll
    for (int ks = 0; ks < 4; ++ks) {
        bfrag8 b[4];
        #pragma unroll
        for (int j = 0; j < 4; ++j) {
            int r = min(row0 + j * 16 + lr, NN - 1);
            b[j] = *(const bfrag8*)&Abf[(size_t)r * 128 + (ks * 4 + kg) * 8];
        }
        #pragma unroll
        for (int j = 0; j < 4; ++j)
            #pragma unroll
            for (int i = 0; i < 4; ++i)
                acc[j][i] = __builtin_amdgcn_mfma_f32_16x16x32_bf16(
                    a[ks][i], b[j], acc[j][i], 0, 0, 0);
    }

    #pragma unroll
    for (int j = 0; j < 4; ++j) {
        int m = row0 + j * 16 + lr;
        if (m < NN) {
            float ds = dis[m];
            #pragma unroll
            for (int i = 0; i < 4; ++i) {
                int colb = wc + i * 16 + kg * 4;
                uint2 pk;
                pk.x = (uint32)f2bf(acc[j][i][0] * ds)
                     | ((uint32)f2bf(acc[j][i][1] * ds) << 16);
                pk.y = (uint32)f2bf(acc[j][i][2] * ds)
                     | ((uint32)f2bf(acc[j][i][3] * ds) << 16);
                *(uint2*)&outbf[(size_t)m * 128 + colb] = pk;
            }
        }
    }
}

// ======== atomic-free CSR build (512-node buckets, 4096-edge blocks) ========

__global__ __launch_bounds__(256) void p1_count(
    const int* __restrict__ ei, int* __restrict__ bcnt)
{
    __shared__ int h[NBUK];
    int aa = blockIdx.x >= EB ? 1 : 0;
    int blk = blockIdx.x - aa * EB;
    const int* col = ei + (size_t)aa * 2 * NE + NE;
    int* bc = bcnt + (size_t)aa * EB * BPAD;
    int t = threadIdx.x;
    if (t < NBUK) h[t] = 0;
    __syncthreads();
    int base = blk * EBLK + t;
    #pragma unroll
    for (int u = 0; u < 16; ++u) {
        int e = base + u * 256;
        if (e < NE) atomicAdd(&h[col[e] >> 9], 1);
    }
    __syncthreads();
    if (t < NBUK) bc[blk * BPAD + t] = h[t];
}

__global__ __launch_bounds__(256) void p2a_scanblocks(
    const int* __restrict__ bcnt, int* __restrict__ pscan,
    int* __restrict__ btot)
{
    __shared__ int s[256];
    int aa = blockIdx.x >= NBUK ? 1 : 0;
    int b = blockIdx.x - aa * NBUK;
    const int* bc = bcnt + (size_t)aa * EB * BPAD;
    int* ps = pscan + (size_t)aa * EB * BPAD;
    int* bt = btot + aa * BPAD;
    int t = threadIdx.x;
    int v[2];
    int loc = 0;
    #pragma unroll
    for (int j = 0; j < 2; ++j) {
        int idx = t * 2 + j;
        v[j] = (idx < EB) ? bc[idx * BPAD + b] : 0;
        loc += v[j];
    }
    s[t] = loc;
    __syncthreads();
    for (int off = 1; off < 256; off <<= 1) {
        int u = (t >= off) ? s[t - off] : 0;
        __syncthreads();
        s[t] += u;
        __syncthreads();
    }
    int pre = s[t] - loc;
    #pragma unroll
    for (int j = 0; j < 2; ++j) {
        int idx = t * 2 + j;
        if (idx < EB) ps[idx * BPAD + b] = pre;
        pre += v[j];
    }
    if (t == 255) bt[b] = s[255];
}

__global__ __launch_bounds__(256) void p2b_scanbuckets(
    const int* __restrict__ btot, int* __restrict__ bbase)
{
    __shared__ int s[256];
    int aa = blockIdx.x;
    const int* bt = btot + aa * BPAD;
    int* bb = bbase + aa * (NBUK + 1);
    int t = threadIdx.x;
    int v = (t < NBUK) ? bt[t] : 0;
    s[t] = v;
    __syncthreads();
    for (int off = 1; off < 256; off <<= 1) {
        int u = (t >= off) ? s[t - off] : 0;
        __syncthreads();
        s[t] += u;
        __syncthreads();
    }
    if (t < NBUK) bb[t] = s[t] - v;
    if (t == NBUK - 1) bb[NBUK] = s[t];
}

__global__ __launch_bounds__(256) void p3_partition(
    const int* __restrict__ ei, const int* __restrict__ pscan,
    const int* __restrict__ bbase, uint2* __restrict__ part)
{
    __shared__ int spre[NBUK];
    __shared__ int cur[NBUK];
    int aa = blockIdx.x >= EB ? 1 : 0;
    int blk = blockIdx.x - aa * EB;
    const int* row = ei + (size_t)aa * 2 * NE;
    const int* col = row + NE;
    const int* ps = pscan + (size_t)aa * EB * BPAD;
    const int* bb = bbase + aa * (NBUK + 1);
    uint2* pt = part + (size_t)aa * NE;
    int t = threadIdx.x;
    if (t < NBUK) {
        spre[t] = bb[t] + ps[blk * BPAD + t];
        cur[t] = 0;
    }
    __syncthreads();
    int base = blk * EBLK + t;
    #pragma unroll
    for (int u = 0; u < 16; ++u) {
        int e = base + u * 256;
        if (e < NE) {
            int c = col[e];
            int b = c >> 9;
            int rk = atomicAdd(&cur[b], 1);
            pt[spre[b] + rk] = make_uint2((uint32)row[e], (uint32)c);
        }
    }
}

__global__ __launch_bounds__(256) void p4_csr(
    const uint2* __restrict__ part, const int* __restrict__ bbase,
    int* __restrict__ row_ptr2, float* __restrict__ dis2,
    int* __restrict__ csr2)
{
    __shared__ int cnt[512];
    __shared__ int sexcl[512];
    __shared__ int cur[512];
    __shared__ int s[256];
    int aa = blockIdx.x >= NBUK ? 1 : 0;
    int b = blockIdx.x - aa * NBUK;
    const uint2* pt = part + (size_t)aa * NE;
    const int* bb = bbase + aa * (NBUK + 1);
    int* rp = row_ptr2 + (size_t)aa * (NN + 1);
    float* ds = dis2 + (size_t)aa * NN;
    int* cs = csr2 + (size_t)aa * NE;
    int t = threadIdx.x;
    int base = bb[b];
    int ecnt = bb[b + 1] - base;
    int n0 = b << 9;
    cnt[t] = 0; cnt[t + 256] = 0;
    cur[t] = 0; cur[t + 256] = 0;
    __syncthreads();
    for (int i = t; i < ecnt; i += 256)
        atomicAdd(&cnt[pt[base + i].y - n0], 1);
    __syncthreads();
    int c0 = cnt[2 * t], c1 = cnt[2 * t + 1];
    int loc = c0 + c1;
    s[t] = loc;
    __syncthreads();
    for (int off = 1; off < 256; off <<= 1) {
        int u = (t >= off) ? s[t - off] : 0;
        __syncthreads();
        s[t] += u;
        __syncthreads();
    }
    int pre = s[t] - loc;
    sexcl[2 * t] = pre;
    sexcl[2 * t + 1] = pre + c0;
    int node = n0 + 2 * t;
    if (node < NN) {
        rp[node] = base + pre;
        ds[node] = rsqrtf((float)(c0 + 1));
    }
    if (node + 1 < NN) {
        rp[node + 1] = base + pre + c0;
        ds[node + 1] = rsqrtf((float)(c1 + 1));
    }
    if (b == 0 && t == 0) rp[NN] = NE;
    __syncthreads();
    for (int i = t; i < ecnt; i += 256) {
        uint2 p = pt[base + i];
        int li = (int)p.y - n0;
        int rk = atomicAdd(&cur[li], 1);
        cs[base + sexcl[li] + rk] = (int)p.x;
    }
}

// agg over both adjacencies; two nodes per wave, scalarized index pipeline
__global__ __launch_bounds__(256) void agg_relu_b(
    const u16* __restrict__ mm2, const int* __restrict__ row_ptr2,
    const int* __restrict__ csr2, const float* __restrict__ dis2,
    u16* __restrict__ h2)
{
    int aa = blockIdx.x >= AB ? 1 : 0;
    int blk = blockIdx.x - aa * AB;
    const u16* mm = mm2 + (size_t)aa * NN * HD;
    const int* row_ptr = row_ptr2 + (size_t)aa * (NN + 1);
    const int* csr_src = csr2 + (size_t)aa * NE;
    const float* dis = dis2 + (size_t)aa * NN;
    u16* out = h2 + (size_t)aa * NN * HD;

    int wid = blk * 4 + (threadIdx.x >> 6);
    int nodeA = wid * 2;
    if (nodeA >= NN) return;
    int nodeB = nodeA + 1;
    uint32 lane = threadIdx.x & 63;
    const uint32* mv = (const uint32*)mm;
    int lan16 = (int)(lane & 15);

    uint32 selfA = mv[(uint32)nodeA * 64u + lane];
    uint32 selfB = mv[(uint32)nodeB * 64u + lane];
    f32x2 accA, accB;
    accA.x = bflo(selfA); accA.y = bfhi(selfA);
    accB.x = bflo(selfB); accB.y = bfhi(selfB);
    int eA = row_ptr[nodeA], e1A = row_ptr[nodeA + 1];
    int eB = e1A,            e1B = row_ptr[nodeB + 1];

    while (eA + 16 <= e1A && eB + 16 <= e1B) {
        uint32 pA = (uint32)csr_src[eA + lan16];
        uint32 pB = (uint32)csr_src[eB + lan16];
        #pragma unroll
        for (int u = 0; u < 16; ++u) {
            uint32 sA = (uint32)__builtin_amdgcn_readlane((int)pA, u);
            uint32 sB = (uint32)__builtin_amdgcn_readlane((int)pB, u);
            uint32 vA = (mv + (size_t)sA * 64u)[lane];
            uint32 vB = (mv + (size_t)sB * 64u)[lane];
            f32x2 tA, tB;
            tA.x = bflo(vA); tA.y = bfhi(vA);
            tB.x = bflo(vB); tB.y = bfhi(vB);
            asm("v_pk_add_f32 %0, %0, %1" : "+v"(accA) : "v"(tA));
            asm("v_pk_add_f32 %0, %0, %1" : "+v"(accB) : "v"(tB));
        }
        eA += 16; eB += 16;
    }
    for (; eA + 16 <= e1A; eA += 16) {
        uint32 pA = (uint32)csr_src[eA + lan16];
        #pragma unroll
        for (int u = 0; u < 16; ++u) {
            uint32 sA = (uint32)__builtin_amdgcn_readlane((int)pA, u);
            uint32 vA = (mv + (size_t)sA * 64u)[lane];
            f32x2 tA;
            tA.x = bflo(vA); tA.y = bfhi(vA);
            asm("v_pk_add_f32 %0, %0, %1" : "+v"(accA) : "v"(tA));
        }
    }
    for (; eB + 16 <= e1B; eB += 16) {
        uint32 pB = (uint32)csr_src[eB + lan16];
        #pragma unroll
        for (int u = 0; u < 16; ++u) {
            uint32 sB = (uint32)__builtin_amdgcn_readlane((int)pB, u);
            uint32 vB = (mv + (size_t)sB * 64u)[lane];
            f32x2 tB;
            tB.x = bflo(vB); tB.y = bfhi(vB);
            asm("v_pk_add_f32 %0, %0, %1" : "+v"(accB) : "v"(tB));
        }
    }
    int remA = e1A - eA, remB = e1B - eB;
    if ((remA | remB) != 0) {
        if (remA > 0 && remB > 0 && remA <= 8 && remB <= 8) {
            uint32 pA = (uint32)csr_src[min(eA + (int)(lane & 7), e1A - 1)];
            uint32 pB = (uint32)csr_src[min(eB + (int)(lane & 7), e1B - 1)];
            #pragma unroll
            for (int u = 0; u < 8; ++u) {
                uint32 sA = (uint32)__builtin_amdgcn_readlane((int)pA, u);
                uint32 sB = (uint32)__builtin_amdgcn_readlane((int)pB, u);
                uint32 vA = (mv + (size_t)sA * 64u)[lane];
                uint32 vB = (mv + (size_t)sB * 64u)[lane];
                float mA = (eA + u < e1A) ? 1.f : 0.f;
                float mB = (eB + u < e1B) ? 1.f : 0.f;
                f32x2 tA, tB, kA, kB;
                tA.x = bflo(vA); tA.y = bfhi(vA); kA.x = mA; kA.y = mA;
                tB.x = bflo(vB); tB.y = bfhi(vB); kB.x = mB; kB.y = mB;
                asm("v_pk_fma_f32 %0, %1, %2, %0" : "+v"(accA) : "v"(tA), "v"(kA));
                asm("v_pk_fma_f32 %0, %1, %2, %0" : "+v"(accB) : "v"(tB), "v"(kB));
            }
        } else {
            uint32 pA = 0, pB = 0;
            if (remA > 0) pA = (uint32)csr_src[min(eA + lan16, e1A - 1)];
            if (remB > 0) pB = (uint32)csr_src[min(eB + lan16, e1B - 1)];
            if (remA > 0 && remB > 0) {
                #pragma unroll
                for (int u = 0; u < 16; ++u) {
                    uint32 sA = (uint32)__builtin_amdgcn_readlane((int)pA, u);
                    uint32 sB = (uint32)__builtin_amdgcn_readlane((int)pB, u);
                    uint32 vA = (mv + (size_t)sA * 64u)[lane];
                    uint32 vB = (mv + (size_t)sB * 64u)[lane];
                    float mA = (eA + u < e1A) ? 1.f : 0.f;
                    float mB = (eB + u < e1B) ? 1.f : 0.f;
                    f32x2 tA, tB, kA, kB;
                    tA.x = bflo(vA); tA.y = bfhi(vA); kA.x = mA; kA.y = mA;
                    tB.x = bflo(vB); tB.y = bfhi(vB); kB.x = mB; kB.y = mB;
                    asm("v_pk_fma_f32 %0, %1, %2, %0" : "+v"(accA) : "v"(tA), "v"(kA));
                    asm("v_pk_fma_f32 %0, %1, %2, %0" : "+v"(accB) : "v"(tB), "v"(kB));
                }
            } else if (remA > 0) {
                #pragma unroll
                for (int u = 0; u < 16; ++u) {
                    uint32 sA = (uint32)__builtin_amdgcn_readlane((int)pA, u);
                    uint32 vA = (mv + (size_t)sA * 64u)[lane];
                    float mA = (eA + u < e1A) ? 1.f : 0.f;
                    f32x2 tA, kA;
                    tA.x = bflo(vA); tA.y = bfhi(vA); kA.x = mA; kA.y = mA;
                    asm("v_pk_fma_f32 %0, %1, %2, %0" : "+v"(accA) : "v"(tA), "v"(kA));
                }
            } else {
                #pragma unroll
                for (int u = 0; u < 16; ++u) {
                    uint32 sB = (uint32)__builtin_amdgcn_readlane((int)pB, u);
                    uint32 vB = (mv + (size_t)sB * 64u)[lane];
                    float mB = (eB + u < e1B) ? 1.f : 0.f;
                    f32x2 tB, kB;
                    tB.x = bflo(vB); tB.y = bfhi(vB); kB.x = mB; kB.y = mB;
                    asm("v_pk_fma_f32 %0, %1, %2, %0" : "+v"(accB) : "v"(tB), "v"(kB));
                }
            }
        }
    }

    float dA = dis[nodeA], dB = dis[nodeB];
    uint32 poA = (uint32)f2bf(fmaxf(dA * accA.x, 0.f))
               | ((uint32)f2bf(fmaxf(dA * accA.y, 0.f)) << 16);
    uint32 poB = (uint32)f2bf(fmaxf(dB * accB.x, 0.f))
               | ((uint32)f2bf(fmaxf(dB * accB.y, 0.f)) << 16);
    ((uint32*)out)[(uint32)nodeA * 64u + lane] = poA;
    ((uint32*)out)[(uint32)nodeB * 64u + lane] = poB;
}

// pooled[batch[n]][aa*128 + 2c..2c+1] += h2[aa][n][2c..2c+1], both adjacencies
__global__ __launch_bounds__(64) void pool_add_b(
    const u16* __restrict__ h2, const int* __restrict__ batch,
    float* __restrict__ pooled)
{
    int aa = blockIdx.x >= PB ? 1 : 0;
    int blk = blockIdx.x - aa * PB;
    const uint32* hv = (const uint32*)(h2 + (size_t)aa * NN * HD);
    int aoff = aa * HD;
    int c2 = threadIdx.x;
    int n0 = blk * 64;
    int nend = min(n0 + 64, NN);
    int cur = batch[n0];
    float ax = 0.f, ay = 0.f;
    for (int n = n0; n < nend; ++n) {
        int g = batch[n];
        if (g != cur) {
            atomicAdd(&pooled[(size_t)cur * 256 + aoff + 2 * c2], ax);
            atomicAdd(&pooled[(size_t)cur * 256 + aoff + 2 * c2 + 1], ay);
            ax = 0.f; ay = 0.f;
            cur = g;
        }
        uint32 v = hv[(size_t)n * 64 + c2];
        ax += bflo(v);
        ay += bfhi(v);
    }
    atomicAdd(&pooled[(size_t)cur * 256 + aoff + 2 * c2], ax);
    atomicAdd(&pooled[(size_t)cur * 256 + aoff + 2 * c2 + 1], ay);
}

// out[g] = relu(pooled[g] @ w1 + b1) @ w2 + b2
__global__ __launch_bounds__(128) void head(
    const float* __restrict__ pooled,
    const float* __restrict__ w1, const float* __restrict__ b1,
    const float* __restrict__ w2, const float* __restrict__ b2,
    float* __restrict__ out)
{
    __shared__ float sp[256];
    __shared__ float sg[128];
    int g = blockIdx.x, t = threadIdx.x;
    sp[t] = pooled[(size_t)g * 256 + t];
    sp[t + 128] = pooled[(size_t)g * 256 + 128 + t];
    __syncthreads();
    float acc = b1[t];
    #pragma unroll 8
    for (int k = 0; k < 256; ++k) acc = fmaf(sp[k], w1[k * 128 + t], acc);
    sg[t] = fmaxf(acc, 0.f) * w2[t];
    __syncthreads();
    for (int s2 = 64; s2 > 0; s2 >>= 1) {
        if (t < s2) sg[t] += sg[t + s2];
        __syncthreads();
    }
    if (t == 0) out[g] = sg[0] + b2[0];
}

extern "C" void kernel_launch(void* const* d_in, const int* in_sizes, int n_in,
                              void* d_out, int out_size, void* d_ws, size_t ws_size,
                              hipStream_t stream) {
    const float* x      = (const float*)d_in[0];
    const int*   ei     = (const int*)d_in[1];
    const int*   batch  = (const int*)d_in[2];
    const float* lin0_w = (const float*)d_in[3];
    const float* lin0_b = (const float*)d_in[4];
    const float* conv_w = (const float*)d_in[5];
    const float* lin1_w = (const float*)d_in[6];
    const float* lin1_b = (const float*)d_in[7];
    const float* lin2_w = (const float*)d_in[8];
    const float* lin2_b = (const float*)d_in[9];
    float* out = (float*)d_out;

    const size_t NB = (size_t)NN * HD;           // floats
    float* x0f    = (float*)d_ws;                // x0bf (NB u16) + xbf (NB u16)
    float* bufA   = x0f + NB;                    // mm2: 2 x NB u16
    float* bufB   = bufA + NB;                   // h2: 2 x NB u16 | part2 alias
    float* pooled = bufB + NB;
    int*   row_ptr2 = (int*)(pooled + (size_t)NG * 256);   // 2*(NN+1)
    float* dis2     = (float*)(row_ptr2 + 2 * (NN + 1));   // 2*NN
    int*   csr2     = (int*)(dis2 + 2 * NN);               // 2*NE
    u16*   wt       = (u16*)(csr2 + 2 * NE);               // 7*HD*HD
    int*   bcnt2    = (int*)(wt + 7 * HD * HD);            // 2*EB*BPAD
    int*   pscan2   = bcnt2 + 2 * EB * BPAD;               // 2*EB*BPAD
    int*   btot2    = pscan2 + 2 * EB * BPAD;              // 2*BPAD
    int*   bbase2   = btot2 + 2 * BPAD;                    // 2*(NBUK+1)

    u16* x0bf    = (u16*)x0f;
    u16* xbf     = (u16*)(x0f + NB / 2);
    u16* mm2     = (u16*)bufA;
    u16* h2      = (u16*)bufB;
    uint2* part2 = (uint2*)bufB;   // dead once first agg writes h2

    hipMemsetAsync(pooled, 0, (size_t)NG * 256 * sizeof(float), stream);

    prep<<<6250 + 7, 256, 0, stream>>>(x, conv_w, lin0_w, xbf, wt);

    // CSR build for BOTH adjacencies, batched launches
    p1_count<<<2 * EB, 256, 0, stream>>>(ei, bcnt2);
    p2a_scanblocks<<<2 * NBUK, 256, 0, stream>>>(bcnt2, pscan2, btot2);
    p2b_scanbuckets<<<2, 256, 0, stream>>>(btot2, bbase2);
    p3_partition<<<2 * EB, 256, 0, stream>>>(ei, pscan2, bbase2, part2);
    p4_csr<<<2 * NBUK, 256, 0, stream>>>(part2, bbase2, row_ptr2, dis2, csr2);

    // x0 = bf16(relu(x @ lin0_w + lin0_b))
    gemm_mfma<<<GB, 256, 0, stream>>>(xbf, wt + 6 * HD * HD, x0bf, lin0_b);

    // layer chain, both adjacencies per launch
    for (int l = 0; l < NLAY; ++l) {
        gemm_mfma_b<<<2 * GB, 256, 0, stream>>>(
            l == 0 ? x0bf : h2, l == 0 ? 1 : 0, wt, l, mm2, dis2);
        agg_relu_b<<<2 * AB, 256, 0, stream>>>(mm2, row_ptr2, csr2, dis2, h2);
    }

    pool_add_b<<<2 * PB, 64, 0, stream>>>(h2, batch, pooled);

    head<<<NG, 128, 0, stream>>>(pooled, lin1_w, lin1_b, lin2_w, lin2_b, out);
}

// Round 17
// 604.345 us; speedup vs baseline: 1.4833x; 1.0259x over previous
//
#include <hip/hip_runtime.h>

#define NN 100000
#define NE 1600000
#define NADJ 2
#define NLAY 3
#define HD 128
#define NG 1024

#define EBLK 4096    // edges per partition block
#define EB   391     // ceil(NE/EBLK)
#define NBUK 196     // col buckets of 512 nodes
#define BPAD 200     // padded bucket stride
#define GB   782     // gemm blocks per adjacency
#define AB   12500   // agg blocks per adjacency (NN/8)
#define PB   1563    // pool blocks per adjacency

typedef unsigned int uint32;
typedef unsigned short u16;

typedef __attribute__((ext_vector_type(8))) short bfrag8;   // 8 bf16 (4 VGPR)
typedef __attribute__((ext_vector_type(4))) float f32x4;
typedef __attribute__((ext_vector_type(2))) float f32x2;

__device__ __forceinline__ u16 f2bf(float f) {   // RNE pack
    uint32 u = __float_as_uint(f);
    u += 0x7FFFu + ((u >> 16) & 1u);
    return (u16)(u >> 16);
}
__device__ __forceinline__ float bflo(uint32 u) { return __uint_as_float(u << 16); }
__device__ __forceinline__ float bfhi(uint32 u) { return __uint_as_float(u & 0xFFFF0000u); }

// one-time: wt[b][n][k] = bf16(W_b[k][n]); b in [0,6) -> conv, b==6 -> lin0_w
__global__ void wt_prep(const float* __restrict__ conv_w,
                        const float* __restrict__ lin0_w, u16* __restrict__ wt) {
    const float* W = (blockIdx.x < 6) ? conv_w + (size_t)blockIdx.x * HD * HD
                                      : lin0_w;
    u16* o = wt + (size_t)blockIdx.x * HD * HD;
    for (int i = 0; i < 64; ++i) {
        int idx = i * 256 + threadIdx.x;
        int n = idx >> 7, k = idx & 127;
        o[idx] = f2bf(W[k * 128 + n]);
    }
}

// lin0 GEMM: reads x (f32) directly, converts fragments in-register (same RNE),
// swapped operands, packed bf16 stores. Saves the 51 MB xbf round-trip.
__global__ __launch_bounds__(256) void gemm_lin0(
    const float* __restrict__ x, const u16* __restrict__ Wt,
    u16* __restrict__ outbf, const float* __restrict__ bias)
{
    const int wid = blockIdx.x * 4 + (threadIdx.x >> 6);
    const int lane = threadIdx.x & 63;
    const int row0 = (wid >> 1) * 64;
    if (row0 >= NN) return;
    const int wc = (wid & 1) * 64;
    const int lr = lane & 15, kg = lane >> 4;

    bfrag8 a[4][4];
    #pragma unroll
    for (int ks = 0; ks < 4; ++ks)
        #pragma unroll
        for (int i = 0; i < 4; ++i)
            a[ks][i] = *(const bfrag8*)&Wt[(size_t)(wc + i * 16 + lr) * 128
                                           + (ks * 4 + kg) * 8];

    const f32x4 z = {0.f, 0.f, 0.f, 0.f};
    f32x4 acc[4][4];
    #pragma unroll
    for (int j = 0; j < 4; ++j)
        #pragma unroll
        for (int i = 0; i < 4; ++i) acc[j][i] = z;

    #pragma unroll
    for (int ks = 0; ks < 4; ++ks) {
        bfrag8 b[4];
        #pragma unroll
        for (int j = 0; j < 4; ++j) {
            int r = min(row0 + j * 16 + lr, NN - 1);
            const float* xr = x + (size_t)r * 128 + (ks * 4 + kg) * 8;
            float4 lo = *(const float4*)xr;
            float4 hi = *(const float4*)(xr + 4);
            bfrag8 fr;
            fr[0] = (short)f2bf(lo.x); fr[1] = (short)f2bf(lo.y);
            fr[2] = (short)f2bf(lo.z); fr[3] = (short)f2bf(lo.w);
            fr[4] = (short)f2bf(hi.x); fr[5] = (short)f2bf(hi.y);
            fr[6] = (short)f2bf(hi.z); fr[7] = (short)f2bf(hi.w);
            b[j] = fr;
        }
        #pragma unroll
        for (int j = 0; j < 4; ++j)
            #pragma unroll
            for (int i = 0; i < 4; ++i)
                acc[j][i] = __builtin_amdgcn_mfma_f32_16x16x32_bf16(
                    a[ks][i], b[j], acc[j][i], 0, 0, 0);
    }

    #pragma unroll
    for (int j = 0; j < 4; ++j) {
        int m = row0 + j * 16 + lr;
        if (m < NN) {
            #pragma unroll
            for (int i = 0; i < 4; ++i) {
                int colb = wc + i * 16 + kg * 4;
                float4 bb = *(const float4*)&bias[colb];
                float v0 = fmaxf(acc[j][i][0] + bb.x, 0.f);
                float v1 = fmaxf(acc[j][i][1] + bb.y, 0.f);
                float v2 = fmaxf(acc[j][i][2] + bb.z, 0.f);
                float v3 = fmaxf(acc[j][i][3] + bb.w, 0.f);
                uint2 pk;
                pk.x = (uint32)f2bf(v0) | ((uint32)f2bf(v1) << 16);
                pk.y = (uint32)f2bf(v2) | ((uint32)f2bf(v3) << 16);
                *(uint2*)&outbf[(size_t)m * 128 + colb] = pk;
            }
        }
    }
}

// conv GEMM, both adjacencies batched: mm2[aa] = bf16(dis[aa] .* (h[aa] @ W[aa,l]))
__global__ __launch_bounds__(256) void gemm_mfma_b(
    const u16* __restrict__ hbase, int shared, const u16* __restrict__ wt,
    int l, u16* __restrict__ mm2, const float* __restrict__ dis2)
{
    int aa = blockIdx.x >= GB ? 1 : 0;
    int bblk = blockIdx.x - aa * GB;
    const u16* Abf = shared ? hbase : hbase + (size_t)aa * NN * HD;
    const u16* Wt = wt + (size_t)(aa * NLAY + l) * HD * HD;
    u16* outbf = mm2 + (size_t)aa * NN * HD;
    const float* dis = dis2 + (size_t)aa * NN;

    const int wid = bblk * 4 + (threadIdx.x >> 6);
    const int lane = threadIdx.x & 63;
    const int row0 = (wid >> 1) * 64;
    if (row0 >= NN) return;
    const int wc = (wid & 1) * 64;
    const int lr = lane & 15, kg = lane >> 4;

    bfrag8 a[4][4];
    #pragma unroll
    for (int ks = 0; ks < 4; ++ks)
        #pragma unroll
        for (int i = 0; i < 4; ++i)
            a[ks][i] = *(const bfrag8*)&Wt[(size_t)(wc + i * 16 + lr) * 128
                                           + (ks * 4 + kg) * 8];

    const f32x4 z = {0.f, 0.f, 0.f, 0.f};
    f32x4 acc[4][4];
    #pragma unroll
    for (int j = 0; j < 4; ++j)
        #pragma unroll
        for (int i = 0; i < 4; ++i) acc[j][i] = z;

    #pragma unroll
    for (int ks = 0; ks < 4; ++ks) {
        bfrag8 b[4];
        #pragma unroll
        for (int j = 0; j < 4; ++j) {
            int r = min(row0 + j * 16 + lr, NN - 1);
            b[j] = *(const bfrag8*)&Abf[(size_t)r * 128 + (ks * 4 + kg) * 8];
        }
        #pragma unroll
        for (int j = 0; j < 4; ++j)
            #pragma unroll
            for (int i = 0; i < 4; ++i)
                acc[j][i] = __builtin_amdgcn_mfma_f32_16x16x32_bf16(
                    a[ks][i], b[j], acc[j][i], 0, 0, 0);
    }

    #pragma unroll
    for (int j = 0; j < 4; ++j) {
        int m = row0 + j * 16 + lr;
        if (m < NN) {
            float ds = dis[m];
            #pragma unroll
            for (int i = 0; i < 4; ++i) {
                int colb = wc + i * 16 + kg * 4;
                uint2 pk;
                pk.x = (uint32)f2bf(acc[j][i][0] * ds)
                     | ((uint32)f2bf(acc[j][i][1] * ds) << 16);
                pk.y = (uint32)f2bf(acc[j][i][2] * ds)
                     | ((uint32)f2bf(acc[j][i][3] * ds) << 16);
                *(uint2*)&outbf[(size_t)m * 128 + colb] = pk;
            }
        }
    }
}

// ======== atomic-free CSR build (512-node buckets, 4096-edge blocks) ========

__global__ __launch_bounds__(256) void p1_count(
    const int* __restrict__ ei, int* __restrict__ bcnt)
{
    __shared__ int h[NBUK];
    int aa = blockIdx.x >= EB ? 1 : 0;
    int blk = blockIdx.x - aa * EB;
    const int* col = ei + (size_t)aa * 2 * NE + NE;
    int* bc = bcnt + (size_t)aa * EB * BPAD;
    int t = threadIdx.x;
    if (t < NBUK) h[t] = 0;
    __syncthreads();
    int base = blk * EBLK + t;
    #pragma unroll
    for (int u = 0; u < 16; ++u) {
        int e = base + u * 256;
        if (e < NE) atomicAdd(&h[col[e] >> 9], 1);
    }
    __syncthreads();
    if (t < NBUK) bc[blk * BPAD + t] = h[t];
}

__global__ __launch_bounds__(256) void p2a_scanblocks(
    const int* __restrict__ bcnt, int* __restrict__ pscan,
    int* __restrict__ btot)
{
    __shared__ int s[256];
    int aa = blockIdx.x >= NBUK ? 1 : 0;
    int b = blockIdx.x - aa * NBUK;
    const int* bc = bcnt + (size_t)aa * EB * BPAD;
    int* ps = pscan + (size_t)aa * EB * BPAD;
    int* bt = btot + aa * BPAD;
    int t = threadIdx.x;
    int v[2];
    int loc = 0;
    #pragma unroll
    for (int j = 0; j < 2; ++j) {
        int idx = t * 2 + j;
        v[j] = (idx < EB) ? bc[idx * BPAD + b] : 0;
        loc += v[j];
    }
    s[t] = loc;
    __syncthreads();
    for (int off = 1; off < 256; off <<= 1) {
        int u = (t >= off) ? s[t - off] : 0;
        __syncthreads();
        s[t] += u;
        __syncthreads();
    }
    int pre = s[t] - loc;
    #pragma unroll
    for (int j = 0; j < 2; ++j) {
        int idx = t * 2 + j;
        if (idx < EB) ps[idx * BPAD + b] = pre;
        pre += v[j];
    }
    if (t == 255) bt[b] = s[255];
}

__global__ __launch_bounds__(256) void p2b_scanbuckets(
    const int* __restrict__ btot, int* __restrict__ bbase)
{
    __shared__ int s[256];
    int aa = blockIdx.x;
    const int* bt = btot + aa * BPAD;
    int* bb = bbase + aa * (NBUK + 1);
    int t = threadIdx.x;
    int v = (t < NBUK) ? bt[t] : 0;
    s[t] = v;
    __syncthreads();
    for (int off = 1; off < 256; off <<= 1) {
        int u = (t >= off) ? s[t - off] : 0;
        __syncthreads();
        s[t] += u;
        __syncthreads();
    }
    if (t < NBUK) bb[t] = s[t] - v;
    if (t == NBUK - 1) bb[NBUK] = s[t];
}

// P3: partition via LDS staging ordered by bucket -> coalesced run writes
__global__ __launch_bounds__(256) void p3_partition(
    const int* __restrict__ ei, const int* __restrict__ pscan,
    const int* __restrict__ bbase, uint2* __restrict__ part)
{
    __shared__ uint2 staged[EBLK];      // 32 KB
    __shared__ int   sdst[EBLK];        // 16 KB
    __shared__ int   spre[NBUK];
    __shared__ int   loff[NBUK];
    __shared__ int   cur[NBUK];
    __shared__ int   s[256];
    int aa = blockIdx.x >= EB ? 1 : 0;
    int blk = blockIdx.x - aa * EB;
    const int* row = ei + (size_t)aa * 2 * NE;
    const int* col = row + NE;
    const int* ps = pscan + (size_t)aa * EB * BPAD;
    const int* bb = bbase + aa * (NBUK + 1);
    uint2* pt = part + (size_t)aa * NE;
    int t = threadIdx.x;
    if (t < NBUK) cur[t] = 0;
    __syncthreads();

    int base = blk * EBLK + t;
    uint32 rr[16], cc[16];
    #pragma unroll
    for (int u = 0; u < 16; ++u) {
        int e = base + u * 256;
        if (e < NE) {
            rr[u] = (uint32)row[e];
            cc[u] = (uint32)col[e];
            atomicAdd(&cur[cc[u] >> 9], 1);
        }
    }
    __syncthreads();
    int v = (t < NBUK) ? cur[t] : 0;
    s[t] = v;
    __syncthreads();
    for (int off = 1; off < 256; off <<= 1) {
        int u = (t >= off) ? s[t - off] : 0;
        __syncthreads();
        s[t] += u;
        __syncthreads();
    }
    if (t < NBUK) {
        loff[t] = s[t] - v;
        spre[t] = bb[t] + ps[blk * BPAD + t];
        cur[t] = 0;
    }
    __syncthreads();
    #pragma unroll
    for (int u = 0; u < 16; ++u) {
        int e = base + u * 256;
        if (e < NE) {
            int b = cc[u] >> 9;
            int rk = atomicAdd(&cur[b], 1);
            int li = loff[b] + rk;
            staged[li] = make_uint2(rr[u], cc[u]);
            sdst[li] = spre[b] + rk;
        }
    }
    __syncthreads();
    int tot = min(NE - blk * EBLK, EBLK);
    for (int i = t; i < tot; i += 256)
        pt[sdst[i]] = staged[i];
}

__global__ __launch_bounds__(256) void p4_csr(
    const uint2* __restrict__ part, const int* __restrict__ bbase,
    int* __restrict__ row_ptr2, float* __restrict__ dis2,
    int* __restrict__ csr2)
{
    __shared__ int cnt[512];
    __shared__ int sexcl[512];
    __shared__ int cur[512];
    __shared__ int s[256];
    int aa = blockIdx.x >= NBUK ? 1 : 0;
    int b = blockIdx.x - aa * NBUK;
    const uint2* pt = part + (size_t)aa * NE;
    const int* bb = bbase + aa * (NBUK + 1);
    int* rp = row_ptr2 + (size_t)aa * (NN + 1);
    float* ds = dis2 + (size_t)aa * NN;
    int* cs = csr2 + (size_t)aa * NE;
    int t = threadIdx.x;
    int base = bb[b];
    int ecnt = bb[b + 1] - base;
    int n0 = b << 9;
    cnt[t] = 0; cnt[t + 256] = 0;
    cur[t] = 0; cur[t + 256] = 0;
    __syncthreads();
    for (int i = t; i < ecnt; i += 256)
        atomicAdd(&cnt[pt[base + i].y - n0], 1);
    __syncthreads();
    int c0 = cnt[2 * t], c1 = cnt[2 * t + 1];
    int loc = c0 + c1;
    s[t] = loc;
    __syncthreads();
    for (int off = 1; off < 256; off <<= 1) {
        int u = (t >= off) ? s[t - off] : 0;
        __syncthreads();
        s[t] += u;
        __syncthreads();
    }
    int pre = s[t] - loc;
    sexcl[2 * t] = pre;
    sexcl[2 * t + 1] = pre + c0;
    int node = n0 + 2 * t;
    if (node < NN) {
        rp[node] = base + pre;
        ds[node] = rsqrtf((float)(c0 + 1));
    }
    if (node + 1 < NN) {
        rp[node + 1] = base + pre + c0;
        ds[node + 1] = rsqrtf((float)(c1 + 1));
    }
    if (b == 0 && t == 0) rp[NN] = NE;
    __syncthreads();
    for (int i = t; i < ecnt; i += 256) {
        uint2 p = pt[base + i];
        int li = (int)p.y - n0;
        int rk = atomicAdd(&cur[li], 1);
        cs[base + sexcl[li] + rk] = (int)p.x;
    }
}

// agg over both adjacencies; two nodes per wave, scalarized index pipeline
__global__ __launch_bounds__(256) void agg_relu_b(
    const u16* __restrict__ mm2, const int* __restrict__ row_ptr2,
    const int* __restrict__ csr2, const float* __restrict__ dis2,
    u16* __restrict__ h2)
{
    int aa = blockIdx.x >= AB ? 1 : 0;
    int blk = blockIdx.x - aa * AB;
    const u16* mm = mm2 + (size_t)aa * NN * HD;
    const int* row_ptr = row_ptr2 + (size_t)aa * (NN + 1);
    const int* csr_src = csr2 + (size_t)aa * NE;
    const float* dis = dis2 + (size_t)aa * NN;
    u16* out = h2 + (size_t)aa * NN * HD;

    int wid = blk * 4 + (threadIdx.x >> 6);
    int nodeA = wid * 2;
    if (nodeA >= NN) return;
    int nodeB = nodeA + 1;
    uint32 lane = threadIdx.x & 63;
    const uint32* mv = (const uint32*)mm;
    int lan16 = (int)(lane & 15);

    uint32 selfA = mv[(uint32)nodeA * 64u + lane];
    uint32 selfB = mv[(uint32)nodeB * 64u + lane];
    f32x2 accA, accB;
    accA.x = bflo(selfA); accA.y = bfhi(selfA);
    accB.x = bflo(selfB); accB.y = bfhi(selfB);
    int eA = row_ptr[nodeA], e1A = row_ptr[nodeA + 1];
    int eB = e1A,            e1B = row_ptr[nodeB + 1];

    while (eA + 16 <= e1A && eB + 16 <= e1B) {
        uint32 pA = (uint32)csr_src[eA + lan16];
        uint32 pB = (uint32)csr_src[eB + lan16];
        #pragma unroll
        for (int u = 0; u < 16; ++u) {
            uint32 sA = (uint32)__builtin_amdgcn_readlane((int)pA, u);
            uint32 sB = (uint32)__builtin_amdgcn_readlane((int)pB, u);
            uint32 vA = (mv + (size_t)sA * 64u)[lane];
            uint32 vB = (mv + (size_t)sB * 64u)[lane];
            f32x2 tA, tB;
            tA.x = bflo(vA); tA.y = bfhi(vA);
            tB.x = bflo(vB); tB.y = bfhi(vB);
            asm("v_pk_add_f32 %0, %0, %1" : "+v"(accA) : "v"(tA));
            asm("v_pk_add_f32 %0, %0, %1" : "+v"(accB) : "v"(tB));
        }
        eA += 16; eB += 16;
    }
    for (; eA + 16 <= e1A; eA += 16) {
        uint32 pA = (uint32)csr_src[eA + lan16];
        #pragma unroll
        for (int u = 0; u < 16; ++u) {
            uint32 sA = (uint32)__builtin_amdgcn_readlane((int)pA, u);
            uint32 vA = (mv + (size_t)sA * 64u)[lane];
            f32x2 tA;
            tA.x = bflo(vA); tA.y = bfhi(vA);
            asm("v_pk_add_f32 %0, %0, %1" : "+v"(accA) : "v"(tA));
        }
    }
    for (; eB + 16 <= e1B; eB += 16) {
        uint32 pB = (uint32)csr_src[eB + lan16];
        #pragma unroll
        for (int u = 0; u < 16; ++u) {
            uint32 sB = (uint32)__builtin_amdgcn_readlane((int)pB, u);
            uint32 vB = (mv + (size_t)sB * 64u)[lane];
            f32x2 tB;
            tB.x = bflo(vB); tB.y = bfhi(vB);
            asm("v_pk_add_f32 %0, %0, %1" : "+v"(accB) : "v"(tB));
        }
    }
    int remA = e1A - eA, remB = e1B - eB;
    if ((remA | remB) != 0) {
        if (remA > 0 && remB > 0 && remA <= 8 && remB <= 8) {
            uint32 pA = (uint32)csr_src[min(eA + (int)(lane & 7), e1A - 1)];
            uint32 pB = (uint32)csr_src[min(eB + (int)(lane & 7), e1B - 1)];
            #pragma unroll
            for (int u = 0; u < 8; ++u) {
                uint32 sA = (uint32)__builtin_amdgcn_readlane((int)pA, u);
                uint32 sB = (uint32)__builtin_amdgcn_readlane((int)pB, u);
                uint32 vA = (mv + (size_t)sA * 64u)[lane];
                uint32 vB = (mv + (size_t)sB * 64u)[lane];
                float mA = (eA + u < e1A) ? 1.f : 0.f;
                float mB = (eB + u < e1B) ? 1.f : 0.f;
                f32x2 tA, tB, kA, kB;
                tA.x = bflo(vA); tA.y = bfhi(vA); kA.x = mA; kA.y = mA;
                tB.x = bflo(vB); tB.y = bfhi(vB); kB.x = mB; kB.y = mB;
                asm("v_pk_fma_f32 %0, %1, %2, %0" : "+v"(accA) : "v"(tA), "v"(kA));
                asm("v_pk_fma_f32 %0, %1, %2, %0" : "+v"(accB) : "v"(tB), "v"(kB));
            }
        } else {
            uint32 pA = 0, pB = 0;
            if (remA > 0) pA = (uint32)csr_src[min(eA + lan16, e1A - 1)];
            if (remB > 0) pB = (uint32)csr_src[min(eB + lan16, e1B - 1)];
            if (remA > 0 && remB > 0) {
                #pragma unroll
                for (int u = 0; u < 16; ++u) {
                    uint32 sA = (uint32)__builtin_amdgcn_readlane((int)pA, u);
                    uint32 sB = (uint32)__builtin_amdgcn_readlane((int)pB, u);
                    uint32 vA = (mv + (size_t)sA * 64u)[lane];
                    uint32 vB = (mv + (size_t)sB * 64u)[lane];
                    float mA = (eA + u < e1A) ? 1.f : 0.f;
                    float mB = (eB + u < e1B) ? 1.f : 0.f;
                    f32x2 tA, tB, kA, kB;
                    tA.x = bflo(vA); tA.y = bfhi(vA); kA.x = mA; kA.y = mA;
                    tB.x = bflo(vB); tB.y = bfhi(vB); kB.x = mB; kB.y = mB;
                    asm("v_pk_fma_f32 %0, %1, %2, %0" : "+v"(accA) : "v"(tA), "v"(kA));
                    asm("v_pk_fma_f32 %0, %1, %2, %0" : "+v"(accB) : "v"(tB), "v"(kB));
                }
            } else if (remA > 0) {
                #pragma unroll
                for (int u = 0; u < 16; ++u) {
                    uint32 sA = (uint32)__builtin_amdgcn_readlane((int)pA, u);
                    uint32 vA = (mv + (size_t)sA * 64u)[lane];
                    float mA = (eA + u < e1A) ? 1.f : 0.f;
                    f32x2 tA, kA;
                    tA.x = bflo(vA); tA.y = bfhi(vA); kA.x = mA; kA.y = mA;
                    asm("v_pk_fma_f32 %0, %1, %2, %0" : "+v"(accA) : "v"(tA), "v"(kA));
                }
            } else {
                #pragma unroll
                for (int u = 0; u < 16; ++u) {
                    uint32 sB = (uint32)__builtin_amdgcn_readlane((int)pB, u);
                    uint32 vB = (mv + (size_t)sB * 64u)[lane];
                    float mB = (eB + u < e1B) ? 1.f : 0.f;
                    f32x2 tB, kB;
                    tB.x = bflo(vB); tB.y = bfhi(vB); kB.x = mB; kB.y = mB;
                    asm("v_pk_fma_f32 %0, %1, %2, %0" : "+v"(accB) : "v"(tB), "v"(kB));
                }
            }
        }
    }

    float dA = dis[nodeA], dB = dis[nodeB];
    uint32 poA = (uint32)f2bf(fmaxf(dA * accA.x, 0.f))
               | ((uint32)f2bf(fmaxf(dA * accA.y, 0.f)) << 16);
    uint32 poB = (uint32)f2bf(fmaxf(dB * accB.x, 0.f))
               | ((uint32)f2bf(fmaxf(dB * accB.y, 0.f)) << 16);
    ((uint32*)out)[(uint32)nodeA * 64u + lane] = poA;
    ((uint32*)out)[(uint32)nodeB * 64u + lane] = poB;
}

// pooled[batch[n]][aa*128 + 2c..2c+1] += h2[aa][n][2c..2c+1], both adjacencies
__global__ __launch_bounds__(64) void pool_add_b(
    const u16* __restrict__ h2, const int* __restrict__ batch,
    float* __restrict__ pooled)
{
    int aa = blockIdx.x >= PB ? 1 : 0;
    int blk = blockIdx.x - aa * PB;
    const uint32* hv = (const uint32*)(h2 + (size_t)aa * NN * HD);
    int aoff = aa * HD;
    int c2 = threadIdx.x;
    int n0 = blk * 64;
    int nend = min(n0 + 64, NN);
    int cur = batch[n0];
    float ax = 0.f, ay = 0.f;
    for (int n = n0; n < nend; ++n) {
        int g = batch[n];
        if (g != cur) {
            atomicAdd(&pooled[(size_t)cur * 256 + aoff + 2 * c2], ax);
            atomicAdd(&pooled[(size_t)cur * 256 + aoff + 2 * c2 + 1], ay);
            ax = 0.f; ay = 0.f;
            cur = g;
        }
        uint32 v = hv[(size_t)n * 64 + c2];
        ax += bflo(v);
        ay += bfhi(v);
    }
    atomicAdd(&pooled[(size_t)cur * 256 + aoff + 2 * c2], ax);
    atomicAdd(&pooled[(size_t)cur * 256 + aoff + 2 * c2 + 1], ay);
}

// out[g] = relu(pooled[g] @ w1 + b1) @ w2 + b2
__global__ __launch_bounds__(128) void head(
    const float* __restrict__ pooled,
    const float* __restrict__ w1, const float* __restrict__ b1,
    const float* __restrict__ w2, const float* __restrict__ b2,
    float* __restrict__ out)
{
    __shared__ float sp[256];
    __shared__ float sg[128];
    int g = blockIdx.x, t = threadIdx.x;
    sp[t] = pooled[(size_t)g * 256 + t];
    sp[t + 128] = pooled[(size_t)g * 256 + 128 + t];
    __syncthreads();
    float acc = b1[t];
    #pragma unroll 8
    for (int k = 0; k < 256; ++k) acc = fmaf(sp[k], w1[k * 128 + t], acc);
    sg[t] = fmaxf(acc, 0.f) * w2[t];
    __syncthreads();
    for (int s2 = 64; s2 > 0; s2 >>= 1) {
        if (t < s2) sg[t] += sg[t + s2];
        __syncthreads();
    }
    if (t == 0) out[g] = sg[0] + b2[0];
}

extern "C" void kernel_launch(void* const* d_in, const int* in_sizes, int n_in,
                              void* d_out, int out_size, void* d_ws, size_t ws_size,
                              hipStream_t stream) {
    const float* x      = (const float*)d_in[0];
    const int*   ei     = (const int*)d_in[1];
    const int*   batch  = (const int*)d_in[2];
    const float* lin0_w = (const float*)d_in[3];
    const float* lin0_b = (const float*)d_in[4];
    const float* conv_w = (const float*)d_in[5];
    const float* lin1_w = (const float*)d_in[6];
    const float* lin1_b = (const float*)d_in[7];
    const float* lin2_w = (const float*)d_in[8];
    const float* lin2_b = (const float*)d_in[9];
    float* out = (float*)d_out;

    const size_t NB = (size_t)NN * HD;           // floats
    float* x0f    = (float*)d_ws;                // x0bf (NB u16); rest unused
    float* bufA   = x0f + NB;                    // mm2: 2 x NB u16
    float* bufB   = bufA + NB;                   // h2: 2 x NB u16 | part2 alias
    float* pooled = bufB + NB;
    int*   row_ptr2 = (int*)(pooled + (size_t)NG * 256);   // 2*(NN+1)
    float* dis2     = (float*)(row_ptr2 + 2 * (NN + 1));   // 2*NN
    int*   csr2     = (int*)(dis2 + 2 * NN);               // 2*NE
    u16*   wt       = (u16*)(csr2 + 2 * NE);               // 7*HD*HD
    int*   bcnt2    = (int*)(wt + 7 * HD * HD);            // 2*EB*BPAD
    int*   pscan2   = bcnt2 + 2 * EB * BPAD;               // 2*EB*BPAD
    int*   btot2    = pscan2 + 2 * EB * BPAD;              // 2*BPAD
    int*   bbase2   = btot2 + 2 * BPAD;                    // 2*(NBUK+1)

    u16* x0bf    = (u16*)x0f;
    u16* mm2     = (u16*)bufA;
    u16* h2      = (u16*)bufB;
    uint2* part2 = (uint2*)bufB;   // dead once first agg writes h2

    hipMemsetAsync(pooled, 0, (size_t)NG * 256 * sizeof(float), stream);

    wt_prep<<<7, 256, 0, stream>>>(conv_w, lin0_w, wt);

    // CSR build for BOTH adjacencies, batched launches
    p1_count<<<2 * EB, 256, 0, stream>>>(ei, bcnt2);
    p2a_scanblocks<<<2 * NBUK, 256, 0, stream>>>(bcnt2, pscan2, btot2);
    p2b_scanbuckets<<<2, 256, 0, stream>>>(btot2, bbase2);
    p3_partition<<<2 * EB, 256, 0, stream>>>(ei, pscan2, bbase2, part2);
    p4_csr<<<2 * NBUK, 256, 0, stream>>>(part2, bbase2, row_ptr2, dis2, csr2);

    // x0 = bf16(relu(x @ lin0_w + lin0_b)), f32 input converted in-register
    gemm_lin0<<<GB, 256, 0, stream>>>(x, wt + 6 * HD * HD, x0bf, lin0_b);

    // layer chain, both adjacencies per launch
    for (int l = 0; l < NLAY; ++l) {
        gemm_mfma_b<<<2 * GB, 256, 0, stream>>>(
            l == 0 ? x0bf : h2, l == 0 ? 1 : 0, wt, l, mm2, dis2);
        agg_relu_b<<<2 * AB, 256, 0, stream>>>(mm2, row_ptr2, csr2, dis2, h2);
    }

    pool_add_b<<<2 * PB, 64, 0, stream>>>(h2, batch, pooled);

    head<<<NG, 128, 0, stream>>>(pooled, lin1_w, lin1_b, lin2_w, lin2_b, out);
}